// Round 1
// baseline (218.306 us; speedup 1.0000x reference)
//
#include <hip/hip_runtime.h>
#include <hip/hip_bf16.h>
#include <cstdint>

#define DI __device__ __forceinline__

using u16x8  = __attribute__((ext_vector_type(8))) unsigned short;
using bf16x8 = __attribute__((ext_vector_type(8))) __bf16;
using f32x4  = __attribute__((ext_vector_type(4))) float;

// ---------- helpers ----------

DI unsigned short f2bf(float f) {           // RNE float -> bf16 bits
  unsigned u = __builtin_bit_cast(unsigned, f);
  u += 0x7fffu + ((u >> 16) & 1u);
  return (unsigned short)(u >> 16);
}

DI void gld_lds16(const void* g, void* l) { // async global->LDS, 16B/lane, dest = wave-uniform base + lane*16
  __builtin_amdgcn_global_load_lds(
      (const __attribute__((address_space(1))) void*)(uintptr_t)g,
      (__attribute__((address_space(3))) void*)(uint32_t)(uintptr_t)l,
      16, 0, 0);
}

// ---------- conversion kernels ----------

__global__ __launch_bounds__(256) void cvt_bf16_kernel(const float* __restrict__ in,
                                                        unsigned short* __restrict__ out, int n) {
  int i = (blockIdx.x * 256 + threadIdx.x) * 8;
  if (i >= n) return;
  float4 v0 = *(const float4*)(in + i);
  float4 v1 = *(const float4*)(in + i + 4);
  u16x8 o;
  o[0] = f2bf(v0.x); o[1] = f2bf(v0.y); o[2] = f2bf(v0.z); o[3] = f2bf(v0.w);
  o[4] = f2bf(v1.x); o[5] = f2bf(v1.y); o[6] = f2bf(v1.z); o[7] = f2bf(v1.w);
  *(u16x8*)(out + i) = o;
}

// in[K][N] fp32 -> out[N][K] bf16
__global__ __launch_bounds__(256) void transpose_cvt_kernel(const float* __restrict__ in,
                                                             unsigned short* __restrict__ out,
                                                             int K, int N) {
  __shared__ float tile[32][33];
  int n0 = blockIdx.x * 32, k0 = blockIdx.y * 32;
  int tx = threadIdx.x & 31, ty = threadIdx.x >> 5;   // ty in 0..7
#pragma unroll
  for (int i = 0; i < 4; ++i)
    tile[ty * 4 + i][tx] = in[(size_t)(k0 + ty * 4 + i) * N + n0 + tx];
  __syncthreads();
#pragma unroll
  for (int i = 0; i < 4; ++i)
    out[(size_t)(n0 + ty * 4 + i) * K + k0 + tx] = f2bf(tile[tx][ty * 4 + i]);
}

// ---------- TN GEMM: C[M,N] = A[M,K] * B[N,K]^T  (bf16 inputs, fp32 acc) ----------
// 128x128 tile, BK=32, 4 waves in 2x2, frag-order LDS staged by global_load_lds.
// MODE 0: epilogue splits qkv regions, applies RoPE (+0.125 scale on q), scatters to [BH][T][64] bf16.
// MODE 1: plain fp32 store.

template <int MODE>
__global__ __launch_bounds__(256)
void gemm_tn(const unsigned short* __restrict__ A, const unsigned short* __restrict__ B,
             unsigned short* __restrict__ q_out, unsigned short* __restrict__ k_out,
             unsigned short* __restrict__ v_out, float* __restrict__ c_out,
             int M, int N, int K) {
  __shared__ __align__(16) char smem[2][16384];     // per buf: A frags [8][64][16B], B frags +8192
  const int tid = threadIdx.x;
  const int lane = tid & 63, wave = tid >> 6;
  const int wm = wave >> 1, wn = wave & 1;
  const int m0 = blockIdx.y << 7, n0 = blockIdx.x << 7;
  const int r15 = lane & 15, g4 = lane >> 4;

  const size_t Ks = (size_t)K;
  const unsigned short* aptr = A + (size_t)(m0 + wave * 16 + r15) * Ks + g4 * 8;
  const unsigned short* bptr = B + (size_t)(n0 + wave * 16 + r15) * Ks + g4 * 8;

  f32x4 acc[4][4] = {};
  const int NT = K >> 5;

  auto stage = [&](int buf, int kt) {
    const unsigned short* ak = aptr + kt * 32;
    const unsigned short* bk = bptr + kt * 32;
    char* sA = &smem[buf][0] + wave * 1024;
    char* sB = &smem[buf][8192] + wave * 1024;
    gld_lds16(ak, sA);
    gld_lds16(ak + 64 * Ks, sA + 4096);
    gld_lds16(bk, sB);
    gld_lds16(bk + 64 * Ks, sB + 4096);
  };

  stage(0, 0);
  __syncthreads();
  for (int kt = 0; kt < NT; ++kt) {
    int buf = kt & 1;
    if (kt + 1 < NT) stage(buf ^ 1, kt + 1);
    const char* base = &smem[buf][0];
    bf16x8 af[4], bfr[4];
#pragma unroll
    for (int mt = 0; mt < 4; ++mt)
      af[mt] = *(const bf16x8*)(base + ((wm * 4 + mt) * 64 + lane) * 16);
#pragma unroll
    for (int nt = 0; nt < 4; ++nt)
      bfr[nt] = *(const bf16x8*)(base + 8192 + ((wn * 4 + nt) * 64 + lane) * 16);
#pragma unroll
    for (int mt = 0; mt < 4; ++mt)
#pragma unroll
      for (int nt = 0; nt < 4; ++nt)
        acc[mt][nt] = __builtin_amdgcn_mfma_f32_16x16x32_bf16(af[mt], bfr[nt], acc[mt][nt], 0, 0, 0);
    __syncthreads();
  }

  const int gm0 = m0 + wm * 64, gn0 = n0 + wn * 64;
  if constexpr (MODE == 0) {
    const int region = gn0 >> 10;               // 0=q 1=k 2=v (wave spans one 64-col head)
    const int h = (gn0 & 1023) >> 6;
    if (region <= 1) {
      unsigned short* dst = (region == 0) ? q_out : k_out;
      const float qs = (region == 0) ? 0.125f : 1.0f;   // fold 1/sqrt(64) into q
#pragma unroll
      for (int mt = 0; mt < 4; ++mt) {
#pragma unroll
        for (int r = 0; r < 4; ++r) {
          int mrow = gm0 + mt * 16 + g4 * 4 + r;
          int b = mrow >> 11, t = mrow & 2047;
          unsigned short* rowp = dst + (((size_t)(b * 16 + h) * 2048 + t) << 6);
          float tf = (float)t;
#pragma unroll
          for (int nt = 0; nt < 2; ++nt) {      // d in [0,32); partner reg nt+2 holds d+32
            int j = nt * 16 + r15;
            float invf = exp2f((float)j * -0.4152410118609203f);  // 10000^(-j/32)
            float ang = tf * invf;
            float sv, cv;
            sincosf(ang, &sv, &cv);
            float x1 = acc[mt][nt][r], x2 = acc[mt][nt + 2][r];
            rowp[j]      = f2bf((x1 * cv - x2 * sv) * qs);
            rowp[j + 32] = f2bf((x2 * cv + x1 * sv) * qs);
          }
        }
      }
    } else {
#pragma unroll
      for (int mt = 0; mt < 4; ++mt)
#pragma unroll
        for (int r = 0; r < 4; ++r) {
          int mrow = gm0 + mt * 16 + g4 * 4 + r;
          int b = mrow >> 11, t = mrow & 2047;
          unsigned short* rowp = v_out + (((size_t)(b * 16 + h) * 2048 + t) << 6);
#pragma unroll
          for (int nt = 0; nt < 4; ++nt)
            rowp[nt * 16 + r15] = f2bf(acc[mt][nt][r]);
        }
    }
  } else {
#pragma unroll
    for (int mt = 0; mt < 4; ++mt)
#pragma unroll
      for (int r = 0; r < 4; ++r) {
        int mrow = gm0 + mt * 16 + g4 * 4 + r;
        float* rowp = c_out + (size_t)mrow * N + gn0;
#pragma unroll
        for (int nt = 0; nt < 4; ++nt)
          rowp[nt * 16 + r15] = acc[mt][nt][r];
      }
  }
}

// ---------- causal flash attention ----------
// grid (16 qtiles, 32 bh); 4 waves/block, 32 q-rows/wave, KVBLK=64, D=64.

__global__ __launch_bounds__(256)
void attn_fused(const unsigned short* __restrict__ qb, const unsigned short* __restrict__ kb,
                const unsigned short* __restrict__ vb, unsigned short* __restrict__ attno) {
  __shared__ __align__(16) char ksm[8192];                  // K frag-order [8][64][16B]
  __shared__ __align__(16) unsigned short vsm[64][80];      // V^T [d][kv], pad 16 -> ~4-way reads
  __shared__ __align__(16) unsigned short psm[4][32][80];   // per-wave P [q][kv], pad 16

  const int tid = threadIdx.x, lane = tid & 63, wave = tid >> 6;
  const int r15 = lane & 15, g4 = lane >> 4;
  const int bh = blockIdx.y;
  const int q0 = blockIdx.x << 7;
  const int q0w = q0 + wave * 32;

  const size_t hb = (size_t)bh * 2048 * 64;
  const unsigned short* Qp = qb + hb;
  const unsigned short* Kp = kb + hb;
  const unsigned short* Vp = vb + hb;

  bf16x8 qf[2][2];
#pragma unroll
  for (int mt = 0; mt < 2; ++mt)
#pragma unroll
    for (int kc = 0; kc < 2; ++kc)
      qf[mt][kc] = *(const bf16x8*)(Qp + (size_t)(q0w + mt * 16 + r15) * 64 + kc * 32 + g4 * 8);

  f32x4 o[2][4] = {};
  float mr[2][4], lr[2][4];
#pragma unroll
  for (int mt = 0; mt < 2; ++mt)
#pragma unroll
    for (int r = 0; r < 4; ++r) { mr[mt][r] = -INFINITY; lr[mt][r] = 0.f; }

  const int ntiles = (q0 >> 6) + 2;
  for (int kt = 0; kt < ntiles; ++kt) {
    const int kv0 = kt << 6;
    __syncthreads();                       // all waves done reading previous K/V tile
    // K: frag-order staging (thread covers frags f=wave, wave+4)
#pragma unroll
    for (int i = 0; i < 2; ++i) {
      int f = i * 4 + wave, nt = f >> 1, kc = f & 1;
      gld_lds16(Kp + (size_t)(kv0 + nt * 16 + r15) * 64 + kc * 32 + g4 * 8, ksm + f * 1024);
    }
    // V^T: reg-staged transposed scalar writes
#pragma unroll
    for (int i = 0; i < 2; ++i) {
      int d0 = wave * 8 + i * 32;
      u16x8 v = *(const u16x8*)(Vp + (size_t)(kv0 + lane) * 64 + d0);
#pragma unroll
      for (int j = 0; j < 8; ++j) vsm[d0 + j][lane] = v[j];
    }
    __syncthreads();                       // drains vmcnt (gld_lds) + lgkm (ds writes)

    // QK^T
    f32x4 s[2][4] = {};
#pragma unroll
    for (int nt = 0; nt < 4; ++nt)
#pragma unroll
      for (int kc = 0; kc < 2; ++kc) {
        bf16x8 kf = *(const bf16x8*)(ksm + (nt * 2 + kc) * 1024 + lane * 16);
        s[0][nt] = __builtin_amdgcn_mfma_f32_16x16x32_bf16(qf[0][kc], kf, s[0][nt], 0, 0, 0);
        s[1][nt] = __builtin_amdgcn_mfma_f32_16x16x32_bf16(qf[1][kc], kf, s[1][nt], 0, 0, 0);
      }

    if (kv0 + 63 > q0w) {                  // causal mask (diagonal / beyond tiles)
#pragma unroll
      for (int mt = 0; mt < 2; ++mt)
#pragma unroll
        for (int nt = 0; nt < 4; ++nt)
#pragma unroll
          for (int r = 0; r < 4; ++r)
            if (kv0 + nt * 16 + r15 > q0w + mt * 16 + g4 * 4 + r) s[mt][nt][r] = -1e9f;
    }

    // online softmax (rows replicated across each 16-lane group)
#pragma unroll
    for (int mt = 0; mt < 2; ++mt)
#pragma unroll
      for (int r = 0; r < 4; ++r) {
        float mx = fmaxf(fmaxf(s[mt][0][r], s[mt][1][r]), fmaxf(s[mt][2][r], s[mt][3][r]));
        mx = fmaxf(mx, __shfl_xor(mx, 1));
        mx = fmaxf(mx, __shfl_xor(mx, 2));
        mx = fmaxf(mx, __shfl_xor(mx, 4));
        mx = fmaxf(mx, __shfl_xor(mx, 8));
        float mnew = fmaxf(mr[mt][r], mx);
        float fsc = __expf(mr[mt][r] - mnew);
        float ps = 0.f;
#pragma unroll
        for (int nt = 0; nt < 4; ++nt) {
          float p = __expf(s[mt][nt][r] - mnew);
          s[mt][nt][r] = p;
          ps += p;
        }
        ps += __shfl_xor(ps, 1);
        ps += __shfl_xor(ps, 2);
        ps += __shfl_xor(ps, 4);
        ps += __shfl_xor(ps, 8);
        lr[mt][r] = lr[mt][r] * fsc + ps;
        mr[mt][r] = mnew;
#pragma unroll
        for (int dt = 0; dt < 4; ++dt) o[mt][dt][r] *= fsc;
      }

    // P -> wave-private LDS (A-operand layout source)
#pragma unroll
    for (int mt = 0; mt < 2; ++mt)
#pragma unroll
      for (int nt = 0; nt < 4; ++nt)
#pragma unroll
        for (int r = 0; r < 4; ++r)
          psm[wave][mt * 16 + g4 * 4 + r][nt * 16 + r15] = f2bf(s[mt][nt][r]);

    // PV
#pragma unroll
    for (int kc = 0; kc < 2; ++kc) {
      bf16x8 pa0 = *(const bf16x8*)(&psm[wave][r15][kc * 32 + g4 * 8]);
      bf16x8 pa1 = *(const bf16x8*)(&psm[wave][16 + r15][kc * 32 + g4 * 8]);
#pragma unroll
      for (int dt = 0; dt < 4; ++dt) {
        bf16x8 vf = *(const bf16x8*)(&vsm[dt * 16 + r15][kc * 32 + g4 * 8]);
        o[0][dt] = __builtin_amdgcn_mfma_f32_16x16x32_bf16(pa0, vf, o[0][dt], 0, 0, 0);
        o[1][dt] = __builtin_amdgcn_mfma_f32_16x16x32_bf16(pa1, vf, o[1][dt], 0, 0, 0);
      }
    }
  }

  const int b = bh >> 4, h = bh & 15;
#pragma unroll
  for (int mt = 0; mt < 2; ++mt)
#pragma unroll
    for (int r = 0; r < 4; ++r) {
      float inv = 1.f / lr[mt][r];
      int q = q0w + mt * 16 + g4 * 4 + r;
      unsigned short* rowp = attno + (size_t)(b * 2048 + q) * 1024 + h * 64;
#pragma unroll
      for (int dt = 0; dt < 4; ++dt)
        rowp[dt * 16 + r15] = f2bf(o[mt][dt][r] * inv);
    }
}

// ---------- launcher ----------

extern "C" void kernel_launch(void* const* d_in, const int* in_sizes, int n_in,
                              void* d_out, int out_size, void* d_ws, size_t ws_size,
                              hipStream_t stream) {
  const float* x     = (const float*)d_in[0];
  const float* w_qkv = (const float*)d_in[1];
  const float* w_out = (const float*)d_in[2];
  float* out = (float*)d_out;

  char* ws = (char*)d_ws;
  unsigned short* xb  = (unsigned short*)(ws);                     // 8 MB  x bf16 [4096][1024]
  unsigned short* wqT = (unsigned short*)(ws + (8u << 20));        // 6 MB  w_qkv^T bf16 [3072][1024]
  unsigned short* woT = (unsigned short*)(ws + (14u << 20));       // 2 MB  w_out^T bf16 [1024][1024]
  unsigned short* qb  = (unsigned short*)(ws + (16u << 20));       // 8 MB  q (roped, scaled) [32][2048][64]
  unsigned short* kb  = (unsigned short*)(ws + (24u << 20));       // 8 MB  k (roped)
  unsigned short* vb  = (unsigned short*)(ws + (32u << 20));       // 8 MB  v
  unsigned short* ao  = (unsigned short*)(ws + (40u << 20));       // 8 MB  attn out [4096][1024]

  cvt_bf16_kernel<<<2048, 256, 0, stream>>>(x, xb, 4096 * 1024);
  transpose_cvt_kernel<<<dim3(96, 32), 256, 0, stream>>>(w_qkv, wqT, 1024, 3072);
  transpose_cvt_kernel<<<dim3(32, 32), 256, 0, stream>>>(w_out, woT, 1024, 1024);
  gemm_tn<0><<<dim3(24, 32), 256, 0, stream>>>(xb, wqT, qb, kb, vb, nullptr, 4096, 3072, 1024);
  attn_fused<<<dim3(16, 32), 256, 0, stream>>>(qb, kb, vb, ao);
  gemm_tn<1><<<dim3(8, 32), 256, 0, stream>>>(ao, woT, nullptr, nullptr, nullptr, out, 4096, 1024, 1024);
}

// Round 2
// 193.787 us; speedup vs baseline: 1.1265x; 1.1265x over previous
//
#include <hip/hip_runtime.h>
#include <hip/hip_bf16.h>
#include <cstdint>

#define DI __device__ __forceinline__

using u16x8  = __attribute__((ext_vector_type(8))) unsigned short;
using bf16x8 = __attribute__((ext_vector_type(8))) __bf16;
using f32x4  = __attribute__((ext_vector_type(4))) float;

// ---------- helpers ----------

DI unsigned short f2bf(float f) {           // RNE float -> bf16 bits
  unsigned u = __builtin_bit_cast(unsigned, f);
  u += 0x7fffu + ((u >> 16) & 1u);
  return (unsigned short)(u >> 16);
}

DI void gld_lds16(const void* g, void* l) { // async global->LDS, 16B/lane, dest = wave-uniform base + lane*16
  __builtin_amdgcn_global_load_lds(
      (const __attribute__((address_space(1))) void*)(uintptr_t)g,
      (__attribute__((address_space(3))) void*)(uint32_t)(uintptr_t)l,
      16, 0, 0);
}

// ---------- conversion kernels ----------

__global__ __launch_bounds__(256) void cvt_bf16_kernel(const float* __restrict__ in,
                                                        unsigned short* __restrict__ out, int n) {
  int i = (blockIdx.x * 256 + threadIdx.x) * 8;
  if (i >= n) return;
  float4 v0 = *(const float4*)(in + i);
  float4 v1 = *(const float4*)(in + i + 4);
  u16x8 o;
  o[0] = f2bf(v0.x); o[1] = f2bf(v0.y); o[2] = f2bf(v0.z); o[3] = f2bf(v0.w);
  o[4] = f2bf(v1.x); o[5] = f2bf(v1.y); o[6] = f2bf(v1.z); o[7] = f2bf(v1.w);
  *(u16x8*)(out + i) = o;
}

// in[K][N] fp32 -> out[N][K] bf16
__global__ __launch_bounds__(256) void transpose_cvt_kernel(const float* __restrict__ in,
                                                             unsigned short* __restrict__ out,
                                                             int K, int N) {
  __shared__ float tile[32][33];
  int n0 = blockIdx.x * 32, k0 = blockIdx.y * 32;
  int tx = threadIdx.x & 31, ty = threadIdx.x >> 5;   // ty in 0..7
#pragma unroll
  for (int i = 0; i < 4; ++i)
    tile[ty * 4 + i][tx] = in[(size_t)(k0 + ty * 4 + i) * N + n0 + tx];
  __syncthreads();
#pragma unroll
  for (int i = 0; i < 4; ++i)
    out[(size_t)(n0 + ty * 4 + i) * K + k0 + tx] = f2bf(tile[tx][ty * 4 + i]);
}

// ---------- TN GEMM: C[M,N] = A[M,K] * B[N,K]^T  (bf16 inputs, fp32 acc) ----------
// 128x128 tile, BK=32, 4 waves in 2x2, frag-order LDS staged by global_load_lds.
// MODE 0: epilogue splits qkv regions, RoPE (+0.125 on q), q/k -> [BH][T][64], v -> TRANSPOSED [BH][64][T].
// MODE 1: plain fp32 store.

template <int MODE>
__global__ __launch_bounds__(256)
void gemm_tn(const unsigned short* __restrict__ A, const unsigned short* __restrict__ B,
             unsigned short* __restrict__ q_out, unsigned short* __restrict__ k_out,
             unsigned short* __restrict__ v_out, float* __restrict__ c_out,
             int M, int N, int K) {
  __shared__ __align__(16) char smem[2][16384];     // per buf: A frags [8][64][16B], B frags +8192
  const int tid = threadIdx.x;
  const int lane = tid & 63, wave = tid >> 6;
  const int wm = wave >> 1, wn = wave & 1;
  const int m0 = blockIdx.y << 7, n0 = blockIdx.x << 7;
  const int r15 = lane & 15, g4 = lane >> 4;

  const size_t Ks = (size_t)K;
  const unsigned short* aptr = A + (size_t)(m0 + wave * 16 + r15) * Ks + g4 * 8;
  const unsigned short* bptr = B + (size_t)(n0 + wave * 16 + r15) * Ks + g4 * 8;

  f32x4 acc[4][4] = {};
  const int NT = K >> 5;

  auto stage = [&](int buf, int kt) {
    const unsigned short* ak = aptr + kt * 32;
    const unsigned short* bk = bptr + kt * 32;
    char* sA = &smem[buf][0] + wave * 1024;
    char* sB = &smem[buf][8192] + wave * 1024;
    gld_lds16(ak, sA);
    gld_lds16(ak + 64 * Ks, sA + 4096);
    gld_lds16(bk, sB);
    gld_lds16(bk + 64 * Ks, sB + 4096);
  };

  stage(0, 0);
  __syncthreads();
  for (int kt = 0; kt < NT; ++kt) {
    int buf = kt & 1;
    if (kt + 1 < NT) stage(buf ^ 1, kt + 1);
    const char* base = &smem[buf][0];
    bf16x8 af[4], bfr[4];
#pragma unroll
    for (int mt = 0; mt < 4; ++mt)
      af[mt] = *(const bf16x8*)(base + ((wm * 4 + mt) * 64 + lane) * 16);
#pragma unroll
    for (int nt = 0; nt < 4; ++nt)
      bfr[nt] = *(const bf16x8*)(base + 8192 + ((wn * 4 + nt) * 64 + lane) * 16);
#pragma unroll
    for (int mt = 0; mt < 4; ++mt)
#pragma unroll
      for (int nt = 0; nt < 4; ++nt)
        acc[mt][nt] = __builtin_amdgcn_mfma_f32_16x16x32_bf16(af[mt], bfr[nt], acc[mt][nt], 0, 0, 0);
    __syncthreads();
  }

  const int gm0 = m0 + wm * 64, gn0 = n0 + wn * 64;
  if constexpr (MODE == 0) {
    const int region = gn0 >> 10;               // 0=q 1=k 2=v (wave spans one 64-col head)
    const int h = (gn0 & 1023) >> 6;
    if (region <= 1) {
      unsigned short* dst = (region == 0) ? q_out : k_out;
      const float qs = (region == 0) ? 0.125f : 1.0f;   // fold 1/sqrt(64) into q
#pragma unroll
      for (int mt = 0; mt < 4; ++mt) {
#pragma unroll
        for (int r = 0; r < 4; ++r) {
          int mrow = gm0 + mt * 16 + g4 * 4 + r;
          int b = mrow >> 11, t = mrow & 2047;
          unsigned short* rowp = dst + (((size_t)(b * 16 + h) * 2048 + t) << 6);
          float tf = (float)t;
#pragma unroll
          for (int nt = 0; nt < 2; ++nt) {      // d in [0,32); partner reg nt+2 holds d+32
            int j = nt * 16 + r15;
            float invf = exp2f((float)j * -0.4152410118609203f);  // 10000^(-j/32)
            float ang = tf * invf;
            float sv, cv;
            sincosf(ang, &sv, &cv);
            float x1 = acc[mt][nt][r], x2 = acc[mt][nt + 2][r];
            rowp[j]      = f2bf((x1 * cv - x2 * sv) * qs);
            rowp[j + 32] = f2bf((x2 * cv + x1 * sv) * qs);
          }
        }
      }
    } else {                                    // v -> transposed [BH][64][T]
#pragma unroll
      for (int mt = 0; mt < 4; ++mt)
#pragma unroll
        for (int r = 0; r < 4; ++r) {
          int mrow = gm0 + mt * 16 + g4 * 4 + r;
          int b = mrow >> 11, t = mrow & 2047;
          unsigned short* colp = v_out + ((size_t)(b * 16 + h) * 64) * 2048 + t;
#pragma unroll
          for (int nt = 0; nt < 4; ++nt)
            colp[(size_t)(nt * 16 + r15) * 2048] = f2bf(acc[mt][nt][r]);
        }
    }
  } else {
#pragma unroll
    for (int mt = 0; mt < 4; ++mt)
#pragma unroll
      for (int r = 0; r < 4; ++r) {
        int mrow = gm0 + mt * 16 + g4 * 4 + r;
        float* rowp = c_out + (size_t)mrow * N + gn0;
#pragma unroll
        for (int nt = 0; nt < 4; ++nt)
          rowp[nt * 16 + r15] = acc[mt][nt][r];
      }
  }
}

// ---------- causal flash attention, v2 ----------
// Barrier-free: each wave owns an independent 32-row q-tile. K and V^T fragments are
// direct global->VGPR 16B loads (K/V L2-resident: 4 bh x 512KB = 2MB per XCD via swizzle).
// K double-buffered in registers; V issued at iteration top (latency hidden by QK+softmax).
// Complementary tile pairing -> per-block work exactly constant.

struct Frag8 { bf16x8 f[8]; };

DI void load_k8(const unsigned short* Kp, int kv0, int r15, int g4, Frag8& o) {
#pragma unroll
  for (int i = 0; i < 8; ++i) {
    int nt = i >> 1, kc = i & 1;
    o.f[i] = *(const bf16x8*)(Kp + (size_t)(kv0 + nt * 16 + r15) * 64 + kc * 32 + g4 * 8);
  }
}
DI void load_v8(const unsigned short* Vp, int kv0, int r15, int g4, Frag8& o) {
#pragma unroll
  for (int i = 0; i < 8; ++i) {
    int dt = i >> 1, kc = i & 1;
    o.f[i] = *(const bf16x8*)(Vp + (size_t)(dt * 16 + r15) * 2048 + kv0 + kc * 32 + g4 * 8);
  }
}

__global__ __launch_bounds__(256, 2)
void attn_fused(const unsigned short* __restrict__ qb, const unsigned short* __restrict__ kb,
                const unsigned short* __restrict__ vt, unsigned short* __restrict__ attno) {
  __shared__ __align__(16) unsigned short psm[4][32][72];   // wave-private P [q][kv], pad 8

  const int tid = threadIdx.x, lane = tid & 63, wave = tid >> 6;
  const int r15 = lane & 15, g4 = lane >> 4;

  // bijective swizzle: xcd = wg&7 gets bh in {4*xcd .. 4*xcd+3}; p = tile-pair index
  const int wg = blockIdx.x;                  // 0..511
  const int xcd = wg & 7, kk = (wg >> 3) & 3, p = wg >> 5;
  const int bh = xcd * 4 + kk;
  const int j = (wave < 2) ? (2 * p + wave) : (63 - 2 * p - (wave - 2));  // q-tile 0..63
  const int q0w = j << 5;

  const size_t hb = (size_t)bh * 2048 * 64;
  const unsigned short* Qp = qb + hb;
  const unsigned short* Kp = kb + hb;
  const unsigned short* Vp = vt + hb;         // [64][2048]

  bf16x8 qf[2][2];
#pragma unroll
  for (int mt = 0; mt < 2; ++mt)
#pragma unroll
    for (int kc = 0; kc < 2; ++kc)
      qf[mt][kc] = *(const bf16x8*)(Qp + (size_t)(q0w + mt * 16 + r15) * 64 + kc * 32 + g4 * 8);

  f32x4 o[2][4] = {};
  float mr[2][4], lr[2][4];
#pragma unroll
  for (int mt = 0; mt < 2; ++mt)
#pragma unroll
    for (int r = 0; r < 4; ++r) { mr[mt][r] = -INFINITY; lr[mt][r] = 0.f; }

  const int ntw = (q0w >> 6) + 1;             // kv tiles needed by this wave

  auto process = [&](const Frag8& Kf, const Frag8& Vf, int kv0, bool mask) {
    f32x4 s[2][4] = {};
    __builtin_amdgcn_s_setprio(1);
#pragma unroll
    for (int nt = 0; nt < 4; ++nt)
#pragma unroll
      for (int kc = 0; kc < 2; ++kc) {
        s[0][nt] = __builtin_amdgcn_mfma_f32_16x16x32_bf16(qf[0][kc], Kf.f[nt * 2 + kc], s[0][nt], 0, 0, 0);
        s[1][nt] = __builtin_amdgcn_mfma_f32_16x16x32_bf16(qf[1][kc], Kf.f[nt * 2 + kc], s[1][nt], 0, 0, 0);
      }
    __builtin_amdgcn_s_setprio(0);

    if (mask) {
#pragma unroll
      for (int mt = 0; mt < 2; ++mt)
#pragma unroll
        for (int nt = 0; nt < 4; ++nt)
#pragma unroll
          for (int r = 0; r < 4; ++r)
            if (kv0 + nt * 16 + r15 > q0w + mt * 16 + g4 * 4 + r) s[mt][nt][r] = -1e9f;
    }

    // online softmax (rows live in the lane's 16-lane group)
#pragma unroll
    for (int mt = 0; mt < 2; ++mt)
#pragma unroll
      for (int r = 0; r < 4; ++r) {
        float mx = fmaxf(fmaxf(s[mt][0][r], s[mt][1][r]), fmaxf(s[mt][2][r], s[mt][3][r]));
        mx = fmaxf(mx, __shfl_xor(mx, 1));
        mx = fmaxf(mx, __shfl_xor(mx, 2));
        mx = fmaxf(mx, __shfl_xor(mx, 4));
        mx = fmaxf(mx, __shfl_xor(mx, 8));
        float mnew = fmaxf(mr[mt][r], mx);
        float fsc = __expf(mr[mt][r] - mnew);
        float ps = 0.f;
#pragma unroll
        for (int nt = 0; nt < 4; ++nt) {
          float pv = __expf(s[mt][nt][r] - mnew);
          s[mt][nt][r] = pv;
          ps += pv;
        }
        ps += __shfl_xor(ps, 1);
        ps += __shfl_xor(ps, 2);
        ps += __shfl_xor(ps, 4);
        ps += __shfl_xor(ps, 8);
        lr[mt][r] = lr[mt][r] * fsc + ps;
        mr[mt][r] = mnew;
#pragma unroll
        for (int dt = 0; dt < 4; ++dt) o[mt][dt][r] *= fsc;
      }

    // P -> wave-private LDS (A-operand transpose)
#pragma unroll
    for (int mt = 0; mt < 2; ++mt)
#pragma unroll
      for (int nt = 0; nt < 4; ++nt)
#pragma unroll
        for (int r = 0; r < 4; ++r)
          psm[wave][mt * 16 + g4 * 4 + r][nt * 16 + r15] = f2bf(s[mt][nt][r]);

    // PV
    __builtin_amdgcn_s_setprio(1);
#pragma unroll
    for (int kc = 0; kc < 2; ++kc) {
      bf16x8 pa0 = *(const bf16x8*)(&psm[wave][r15][kc * 32 + g4 * 8]);
      bf16x8 pa1 = *(const bf16x8*)(&psm[wave][16 + r15][kc * 32 + g4 * 8]);
#pragma unroll
      for (int dt = 0; dt < 4; ++dt) {
        o[0][dt] = __builtin_amdgcn_mfma_f32_16x16x32_bf16(pa0, Vf.f[dt * 2 + kc], o[0][dt], 0, 0, 0);
        o[1][dt] = __builtin_amdgcn_mfma_f32_16x16x32_bf16(pa1, Vf.f[dt * 2 + kc], o[1][dt], 0, 0, 0);
      }
    }
    __builtin_amdgcn_s_setprio(0);
  };

  Frag8 ka, kb2, vf;
  load_k8(Kp, 0, r15, g4, ka);
  for (int kt = 0; kt < ntw; kt += 2) {
    load_v8(Vp, kt << 6, r15, g4, vf);
    if (kt + 1 < ntw) load_k8(Kp, (kt + 1) << 6, r15, g4, kb2);
    process(ka, vf, kt << 6, kt == ntw - 1);
    if (kt + 1 >= ntw) break;
    load_v8(Vp, (kt + 1) << 6, r15, g4, vf);
    if (kt + 2 < ntw) load_k8(Kp, (kt + 2) << 6, r15, g4, ka);
    process(kb2, vf, (kt + 1) << 6, kt + 1 == ntw - 1);
  }

  const int b = bh >> 4, h = bh & 15;
#pragma unroll
  for (int mt = 0; mt < 2; ++mt)
#pragma unroll
    for (int r = 0; r < 4; ++r) {
      float inv = 1.f / lr[mt][r];
      int q = q0w + mt * 16 + g4 * 4 + r;
      unsigned short* rowp = attno + (size_t)(b * 2048 + q) * 1024 + h * 64;
#pragma unroll
      for (int dt = 0; dt < 4; ++dt)
        rowp[dt * 16 + r15] = f2bf(o[mt][dt][r] * inv);
    }
}

// ---------- launcher ----------

extern "C" void kernel_launch(void* const* d_in, const int* in_sizes, int n_in,
                              void* d_out, int out_size, void* d_ws, size_t ws_size,
                              hipStream_t stream) {
  const float* x     = (const float*)d_in[0];
  const float* w_qkv = (const float*)d_in[1];
  const float* w_out = (const float*)d_in[2];
  float* out = (float*)d_out;

  char* ws = (char*)d_ws;
  unsigned short* xb  = (unsigned short*)(ws);                     // 8 MB  x bf16 [4096][1024]
  unsigned short* wqT = (unsigned short*)(ws + (8u << 20));        // 6 MB  w_qkv^T bf16 [3072][1024]
  unsigned short* woT = (unsigned short*)(ws + (14u << 20));       // 2 MB  w_out^T bf16 [1024][1024]
  unsigned short* qb  = (unsigned short*)(ws + (16u << 20));       // 8 MB  q (roped, scaled) [32][2048][64]
  unsigned short* kb  = (unsigned short*)(ws + (24u << 20));       // 8 MB  k (roped) [32][2048][64]
  unsigned short* vt  = (unsigned short*)(ws + (32u << 20));       // 8 MB  v TRANSPOSED [32][64][2048]
  unsigned short* ao  = (unsigned short*)(ws + (40u << 20));       // 8 MB  attn out [4096][1024]

  cvt_bf16_kernel<<<2048, 256, 0, stream>>>(x, xb, 4096 * 1024);
  transpose_cvt_kernel<<<dim3(96, 32), 256, 0, stream>>>(w_qkv, wqT, 1024, 3072);
  transpose_cvt_kernel<<<dim3(32, 32), 256, 0, stream>>>(w_out, woT, 1024, 1024);
  gemm_tn<0><<<dim3(24, 32), 256, 0, stream>>>(xb, wqT, qb, kb, vt, nullptr, 4096, 3072, 1024);
  attn_fused<<<512, 256, 0, stream>>>(qb, kb, vt, ao);
  gemm_tn<1><<<dim3(8, 32), 256, 0, stream>>>(ao, woT, nullptr, nullptr, nullptr, out, 4096, 1024, 1024);
}

// Round 7
// 193.716 us; speedup vs baseline: 1.1269x; 1.0004x over previous
//
#include <hip/hip_runtime.h>
#include <hip/hip_bf16.h>
#include <cstdint>

#define DI __device__ __forceinline__

using u16x8  = __attribute__((ext_vector_type(8))) unsigned short;
using u32x4  = __attribute__((ext_vector_type(4))) unsigned int;
using bf16x8 = __attribute__((ext_vector_type(8))) __bf16;
using f32x4  = __attribute__((ext_vector_type(4))) float;

// ---------- helpers ----------

DI unsigned short f2bf(float f) {           // RNE float -> bf16 bits
  unsigned u = __builtin_bit_cast(unsigned, f);
  u += 0x7fffu + ((u >> 16) & 1u);
  return (unsigned short)(u >> 16);
}
DI float bf2f(unsigned short b) {
  unsigned u = (unsigned)b << 16;
  return __builtin_bit_cast(float, u);
}
DI unsigned cvt_pk_bf16(float lo, float hi) {   // packed {lo,hi} -> 2xbf16 (no builtin on gfx950)
  unsigned r;
  asm("v_cvt_pk_bf16_f32 %0, %1, %2" : "=v"(r) : "v"(lo), "v"(hi));
  return r;
}
// gfx950 cross-lane swaps (both operands read-write):
// swap32: a[32..63] <-> b[0..31]
DI void permlane_swap32(unsigned& a, unsigned& b) {
  asm("v_permlane32_swap_b32 %0, %1" : "+v"(a), "+v"(b));
}
// swap16: within each 32-half, a's odd 16-row <-> b's even 16-row
DI void permlane_swap16(unsigned& a, unsigned& b) {
  asm("v_permlane16_swap_b32 %0, %1" : "+v"(a), "+v"(b));
}

DI void gld_lds16(const void* g, void* l) { // async global->LDS, 16B/lane
  __builtin_amdgcn_global_load_lds(
      (const __attribute__((address_space(1))) void*)(uintptr_t)g,
      (__attribute__((address_space(3))) void*)(uint32_t)(uintptr_t)l,
      16, 0, 0);
}

// ---------- conversion kernels ----------

__global__ __launch_bounds__(256) void cvt_bf16_kernel(const float* __restrict__ in,
                                                        unsigned short* __restrict__ out, int n) {
  int i = (blockIdx.x * 256 + threadIdx.x) * 8;
  if (i >= n) return;
  float4 v0 = *(const float4*)(in + i);
  float4 v1 = *(const float4*)(in + i + 4);
  u16x8 o;
  o[0] = f2bf(v0.x); o[1] = f2bf(v0.y); o[2] = f2bf(v0.z); o[3] = f2bf(v0.w);
  o[4] = f2bf(v1.x); o[5] = f2bf(v1.y); o[6] = f2bf(v1.z); o[7] = f2bf(v1.w);
  *(u16x8*)(out + i) = o;
}

// in[K][N] fp32 -> out[N][K] bf16
__global__ __launch_bounds__(256) void transpose_cvt_kernel(const float* __restrict__ in,
                                                             unsigned short* __restrict__ out,
                                                             int K, int N) {
  __shared__ float tile[32][33];
  int n0 = blockIdx.x * 32, k0 = blockIdx.y * 32;
  int tx = threadIdx.x & 31, ty = threadIdx.x >> 5;
#pragma unroll
  for (int i = 0; i < 4; ++i)
    tile[ty * 4 + i][tx] = in[(size_t)(k0 + ty * 4 + i) * N + n0 + tx];
  __syncthreads();
#pragma unroll
  for (int i = 0; i < 4; ++i)
    out[(size_t)(n0 + ty * 4 + i) * K + k0 + tx] = f2bf(tile[tx][ty * 4 + i]);
}

// ---------- TN GEMM: C[M,N] = A[M,K] * B[N,K]^T  (bf16 inputs, fp32 acc) ----------
// MODE 0: epilogue: RoPE; q scaled by 0.125*log2e (exp2-domain softmax); v stored transposed.
// MODE 1: plain fp32 store.

template <int MODE>
__global__ __launch_bounds__(256)
void gemm_tn(const unsigned short* __restrict__ A, const unsigned short* __restrict__ B,
             unsigned short* __restrict__ q_out, unsigned short* __restrict__ k_out,
             unsigned short* __restrict__ v_out, float* __restrict__ c_out,
             int M, int N, int K) {
  __shared__ __align__(16) char smem[2][16384];
  const int tid = threadIdx.x;
  const int lane = tid & 63, wave = tid >> 6;
  const int wm = wave >> 1, wn = wave & 1;
  const int m0 = blockIdx.y << 7, n0 = blockIdx.x << 7;
  const int r15 = lane & 15, g4 = lane >> 4;

  const size_t Ks = (size_t)K;
  const unsigned short* aptr = A + (size_t)(m0 + wave * 16 + r15) * Ks + g4 * 8;
  const unsigned short* bptr = B + (size_t)(n0 + wave * 16 + r15) * Ks + g4 * 8;

  f32x4 acc[4][4] = {};
  const int NT = K >> 5;

  auto stage = [&](int buf, int kt) {
    const unsigned short* ak = aptr + kt * 32;
    const unsigned short* bk = bptr + kt * 32;
    char* sA = &smem[buf][0] + wave * 1024;
    char* sB = &smem[buf][8192] + wave * 1024;
    gld_lds16(ak, sA);
    gld_lds16(ak + 64 * Ks, sA + 4096);
    gld_lds16(bk, sB);
    gld_lds16(bk + 64 * Ks, sB + 4096);
  };

  stage(0, 0);
  __syncthreads();
  for (int kt = 0; kt < NT; ++kt) {
    int buf = kt & 1;
    if (kt + 1 < NT) stage(buf ^ 1, kt + 1);
    const char* base = &smem[buf][0];
    bf16x8 af[4], bfr[4];
#pragma unroll
    for (int mt = 0; mt < 4; ++mt)
      af[mt] = *(const bf16x8*)(base + ((wm * 4 + mt) * 64 + lane) * 16);
#pragma unroll
    for (int nt = 0; nt < 4; ++nt)
      bfr[nt] = *(const bf16x8*)(base + 8192 + ((wn * 4 + nt) * 64 + lane) * 16);
#pragma unroll
    for (int mt = 0; mt < 4; ++mt)
#pragma unroll
      for (int nt = 0; nt < 4; ++nt)
        acc[mt][nt] = __builtin_amdgcn_mfma_f32_16x16x32_bf16(af[mt], bfr[nt], acc[mt][nt], 0, 0, 0);
    __syncthreads();
  }

  const int gm0 = m0 + wm * 64, gn0 = n0 + wn * 64;
  if constexpr (MODE == 0) {
    const int region = gn0 >> 10;               // 0=q 1=k 2=v
    const int h = (gn0 & 1023) >> 6;
    if (region <= 1) {
      unsigned short* dst = (region == 0) ? q_out : k_out;
      const float qs = (region == 0) ? (0.125f * 1.44269504088896341f) : 1.0f;
#pragma unroll
      for (int mt = 0; mt < 4; ++mt) {
#pragma unroll
        for (int r = 0; r < 4; ++r) {
          int mrow = gm0 + mt * 16 + g4 * 4 + r;
          int b = mrow >> 11, t = mrow & 2047;
          unsigned short* rowp = dst + (((size_t)(b * 16 + h) * 2048 + t) << 6);
          float tf = (float)t;
#pragma unroll
          for (int nt = 0; nt < 2; ++nt) {
            int j = nt * 16 + r15;
            float invf = exp2f((float)j * -0.4152410118609203f);  // 10000^(-j/32)
            float ang = tf * invf;
            float sv, cv;
            sincosf(ang, &sv, &cv);
            float x1 = acc[mt][nt][r], x2 = acc[mt][nt + 2][r];
            rowp[j]      = f2bf((x1 * cv - x2 * sv) * qs);
            rowp[j + 32] = f2bf((x2 * cv + x1 * sv) * qs);
          }
        }
      }
    } else {                                    // v -> transposed [BH][64][T]
#pragma unroll
      for (int mt = 0; mt < 4; ++mt)
#pragma unroll
        for (int r = 0; r < 4; ++r) {
          int mrow = gm0 + mt * 16 + g4 * 4 + r;
          int b = mrow >> 11, t = mrow & 2047;
          unsigned short* colp = v_out + ((size_t)(b * 16 + h) * 64) * 2048 + t;
#pragma unroll
          for (int nt = 0; nt < 4; ++nt)
            colp[(size_t)(nt * 16 + r15) * 2048] = f2bf(acc[mt][nt][r]);
        }
    }
  } else {
#pragma unroll
    for (int mt = 0; mt < 4; ++mt)
#pragma unroll
      for (int r = 0; r < 4; ++r) {
        int mrow = gm0 + mt * 16 + g4 * 4 + r;
        float* rowp = c_out + (size_t)mrow * N + gn0;
#pragma unroll
        for (int nt = 0; nt < 4; ++nt)
          rowp[nt * 16 + r15] = acc[mt][nt][r];
      }
  }
}

// ---------- causal flash attention, v4 ----------
// Swapped QK^T (S^T = K*Q^T) -> in-register softmax. P repack to A-frag layout via
// cvt_pk + permlane32_swap + permlane16_swap (zero LDS, pure VALU cross-lane).
// Single-wave blocks; qtiles j>=32 split into 2 kv-chunks (partials merged by
// attn_combine). exp2-domain (log2e folded into q scale).

struct Frag8 { bf16x8 f[8]; };

DI void load_k8(const unsigned short* Kp, int kv0, int r15, int g4, Frag8& o) {
#pragma unroll
  for (int i = 0; i < 8; ++i) {
    int nt = i >> 1, kc = i & 1;
    o.f[i] = *(const bf16x8*)(Kp + (size_t)(kv0 + nt * 16 + r15) * 64 + kc * 32 + g4 * 8);
  }
}
DI void load_v8(const unsigned short* Vp, int kv0, int r15, int g4, Frag8& o) {
#pragma unroll
  for (int i = 0; i < 8; ++i) {
    int dt = i >> 1, kc = i & 1;
    o.f[i] = *(const bf16x8*)(Vp + (size_t)(dt * 16 + r15) * 2048 + kv0 + kc * 32 + g4 * 8);
  }
}

__global__ __launch_bounds__(64, 2)
void attn_fused(const unsigned short* __restrict__ qb, const unsigned short* __restrict__ kb,
                const unsigned short* __restrict__ vt, unsigned short* __restrict__ attno,
                unsigned short* __restrict__ pO, float* __restrict__ pml) {
  const int lane = threadIdx.x;
  const int r15 = lane & 15, g4 = lane >> 4;
  const int bh = blockIdx.y;
  const int cx = blockIdx.x;                  // 0..95
  int j, c;
  if (cx < 32) { j = cx; c = 0; }
  else { int t = cx - 32; j = 32 + (t >> 1); c = t & 1; }
  const int ntw = (j >> 1) + 1;               // kv tiles needed by qtile j
  const int kt0 = c ? 16 : 0;
  const int ktN = (j < 32 || c) ? ntw : 16;
  const bool multi = (j >= 32);
  const int q0w = j << 5;

  const size_t hb = (size_t)bh * 2048 * 64;
  const unsigned short* Qp = qb + hb;
  const unsigned short* Kp = kb + hb;
  const unsigned short* Vp = vt + hb;         // [64][2048]

  bf16x8 qf[2][2];
#pragma unroll
  for (int mq = 0; mq < 2; ++mq)
#pragma unroll
    for (int kc = 0; kc < 2; ++kc)
      qf[mq][kc] = *(const bf16x8*)(Qp + (size_t)(q0w + mq * 16 + r15) * 64 + kc * 32 + g4 * 8);

  f32x4 o[2][4] = {};
  float mr[2] = {-INFINITY, -INFINITY};
  float lr[2] = {0.f, 0.f};

  auto process = [&](const Frag8& Kf, const Frag8& Vf, int kv0, bool mask) {
    f32x4 s[4][2] = {};                       // [nt][mq]: row kv = 16nt+4g4+r, col q = 16mq+r15
    __builtin_amdgcn_s_setprio(1);
#pragma unroll
    for (int nt = 0; nt < 4; ++nt)
#pragma unroll
      for (int kc = 0; kc < 2; ++kc) {
        s[nt][0] = __builtin_amdgcn_mfma_f32_16x16x32_bf16(Kf.f[nt * 2 + kc], qf[0][kc], s[nt][0], 0, 0, 0);
        s[nt][1] = __builtin_amdgcn_mfma_f32_16x16x32_bf16(Kf.f[nt * 2 + kc], qf[1][kc], s[nt][1], 0, 0, 0);
      }
    __builtin_amdgcn_s_setprio(0);

    if (mask) {
#pragma unroll
      for (int nt = 0; nt < 4; ++nt)
#pragma unroll
        for (int mq = 0; mq < 2; ++mq)
#pragma unroll
          for (int r = 0; r < 4; ++r)
            if (kv0 + nt * 16 + g4 * 4 + r > q0w + mq * 16 + r15) s[nt][mq][r] = -1e9f;
    }

    bf16x8 pa[2][2];                          // A-frag for PV: [mq][kc]
#pragma unroll
    for (int mq = 0; mq < 2; ++mq) {
      // ---- row max over 16 in-reg values + 2 butterfly shuffles ----
      float m0 = fmaxf(fmaxf(s[0][mq][0], s[0][mq][1]), fmaxf(s[0][mq][2], s[0][mq][3]));
      float m1 = fmaxf(fmaxf(s[1][mq][0], s[1][mq][1]), fmaxf(s[1][mq][2], s[1][mq][3]));
      float m2 = fmaxf(fmaxf(s[2][mq][0], s[2][mq][1]), fmaxf(s[2][mq][2], s[2][mq][3]));
      float m3 = fmaxf(fmaxf(s[3][mq][0], s[3][mq][1]), fmaxf(s[3][mq][2], s[3][mq][3]));
      float mx = fmaxf(fmaxf(m0, m1), fmaxf(m2, m3));
      mx = fmaxf(mx, __shfl_xor(mx, 16));
      mx = fmaxf(mx, __shfl_xor(mx, 32));
      float mnew = fmaxf(mr[mq], mx);
      float fsc = exp2f(mr[mq] - mnew);
      mr[mq] = mnew;
      // ---- exp2 + sum ----
      float t0 = 0.f, t1 = 0.f, t2 = 0.f, t3 = 0.f;
#pragma unroll
      for (int nt = 0; nt < 4; ++nt) {
        float p0 = exp2f(s[nt][mq][0] - mnew);
        float p1 = exp2f(s[nt][mq][1] - mnew);
        float p2 = exp2f(s[nt][mq][2] - mnew);
        float p3 = exp2f(s[nt][mq][3] - mnew);
        s[nt][mq][0] = p0; s[nt][mq][1] = p1; s[nt][mq][2] = p2; s[nt][mq][3] = p3;
        if (nt == 0) t0 = (p0 + p1) + (p2 + p3);
        if (nt == 1) t1 = (p0 + p1) + (p2 + p3);
        if (nt == 2) t2 = (p0 + p1) + (p2 + p3);
        if (nt == 3) t3 = (p0 + p1) + (p2 + p3);
      }
      float ps = (t0 + t1) + (t2 + t3);
      ps += __shfl_xor(ps, 16);
      ps += __shfl_xor(ps, 32);
      lr[mq] = lr[mq] * fsc + ps;
      // ---- broadcast fsc from softmax rows (r15) to O rows (4g4+r), rescale O ----
#pragma unroll
      for (int r = 0; r < 4; ++r) {
        float fr = __shfl(fsc, (g4 << 2) + r);
#pragma unroll
        for (int dt = 0; dt < 4; ++dt) o[mq][dt][r] *= fr;
      }
      // ---- pack P to bf16 pairs ----
      // lane(g4,r15) holds P[q=mq*16+r15][kv=nt*16+g4*4+{0..3}] -> p32[nt][pi] = kv pair {4g4+2pi, +1}
      unsigned p32[4][2];
#pragma unroll
      for (int nt = 0; nt < 4; ++nt) {
        p32[nt][0] = cvt_pk_bf16(s[nt][mq][0], s[nt][mq][1]);
        p32[nt][1] = cvt_pk_bf16(s[nt][mq][2], s[nt][mq][3]);
      }
      // ---- repack to A-frag layout: lane needs P[q=mq*16+r15][kv=kc*32+g4*8+2w+{0,1}] ----
      // Required permutation swaps (lane-bit5 <-> nt-bit0) then (lane-bit4 <-> word-high-bit):
      // exactly permlane32_swap followed by permlane16_swap. Verified per-quadrant:
      //   after swap32: X=V(nt0=b5, from b5_s=0, b4_s=b4), Y=V(nt0=b5, from b5_s=1, b4_s=b4)
      //   after swap16: X=word(pi), Y=word(2+pi) of target's A-frag.
#pragma unroll
      for (int kc = 0; kc < 2; ++kc) {
        u32x4 w;
#pragma unroll
        for (int pi = 0; pi < 2; ++pi) {
          unsigned a = p32[2 * kc][pi], b = p32[2 * kc + 1][pi];
          permlane_swap32(a, b);
          permlane_swap16(a, b);
          w[pi] = a;
          w[2 + pi] = b;
        }
        pa[mq][kc] = __builtin_bit_cast(bf16x8, w);
      }
    }

    // ---- PV ----
    __builtin_amdgcn_s_setprio(1);
#pragma unroll
    for (int kc = 0; kc < 2; ++kc)
#pragma unroll
      for (int dt = 0; dt < 4; ++dt) {
        o[0][dt] = __builtin_amdgcn_mfma_f32_16x16x32_bf16(pa[0][kc], Vf.f[dt * 2 + kc], o[0][dt], 0, 0, 0);
        o[1][dt] = __builtin_amdgcn_mfma_f32_16x16x32_bf16(pa[1][kc], Vf.f[dt * 2 + kc], o[1][dt], 0, 0, 0);
      }
    __builtin_amdgcn_s_setprio(0);
  };

  Frag8 ka, kb2, vf;
  load_k8(Kp, kt0 << 6, r15, g4, ka);
  for (int kt = kt0; kt < ktN; kt += 2) {
    load_v8(Vp, kt << 6, r15, g4, vf);
    if (kt + 1 < ktN) load_k8(Kp, (kt + 1) << 6, r15, g4, kb2);
    process(ka, vf, kt << 6, kt == ntw - 1);
    if (kt + 1 >= ktN) break;
    load_v8(Vp, (kt + 1) << 6, r15, g4, vf);
    if (kt + 2 < ktN) load_k8(Kp, (kt + 2) << 6, r15, g4, ka);
    process(kb2, vf, (kt + 1) << 6, kt + 1 == ntw - 1);
  }

  if (!multi) {
    const int b = bh >> 4, h = bh & 15;
#pragma unroll
    for (int mq = 0; mq < 2; ++mq) {
      float inv = 1.f / lr[mq];
#pragma unroll
      for (int r = 0; r < 4; ++r) {
        float ir = __shfl(inv, (g4 << 2) + r);
        int q = q0w + mq * 16 + g4 * 4 + r;
        unsigned short* rowp = attno + (size_t)(b * 2048 + q) * 1024 + h * 64;
#pragma unroll
        for (int dt = 0; dt < 4; ++dt)
          rowp[dt * 16 + r15] = f2bf(o[mq][dt][r] * ir);
      }
    }
  } else {
    const int idx = (((bh << 5) + (j - 32)) << 1) + c;
    unsigned short* po = pO + (size_t)idx * 2048;
#pragma unroll
    for (int mq = 0; mq < 2; ++mq)
#pragma unroll
      for (int r = 0; r < 4; ++r)
#pragma unroll
        for (int dt = 0; dt < 4; ++dt)
          po[(mq * 16 + g4 * 4 + r) * 64 + dt * 16 + r15] = f2bf(o[mq][dt][r]);
    if (g4 == 0) {
      float* pm = pml + idx * 64;
#pragma unroll
      for (int mq = 0; mq < 2; ++mq) {
        pm[mq * 16 + r15] = mr[mq];
        pm[32 + mq * 16 + r15] = lr[mq];
      }
    }
  }
}

// ---------- combine partials for qtiles j>=32 (2 chunks each) ----------
__global__ __launch_bounds__(64)
void attn_combine(const unsigned short* __restrict__ pO, const float* __restrict__ pml,
                  unsigned short* __restrict__ attno) {
  const int bx = blockIdx.x;                 // 0..1023
  const int bh = bx >> 5, jj = bx & 31, j = 32 + jj;
  const int t = threadIdx.x;
  const int row = t >> 1, dh = (t & 1) << 5;
  const int i0 = (((bh << 5) + jj) << 1);
  const float* pm0 = pml + i0 * 64;
  const float* pm1 = pm0 + 64;
  float m0 = pm0[row], l0 = pm0[32 + row];
  float m1 = pm1[row], l1 = pm1[32 + row];
  float mg = fmaxf(m0, m1);
  float s0 = exp2f(m0 - mg), s1 = exp2f(m1 - mg);
  float inv = 1.f / (l0 * s0 + l1 * s1);
  s0 *= inv; s1 *= inv;
  const unsigned short* o0 = pO + (size_t)i0 * 2048 + row * 64 + dh;
  const unsigned short* o1 = o0 + 2048;
  const int b = bh >> 4, h = bh & 15;
  unsigned short* dst = attno + (size_t)(b * 2048 + j * 32 + row) * 1024 + h * 64 + dh;
#pragma unroll
  for (int dd = 0; dd < 32; dd += 8) {
    u16x8 a = *(const u16x8*)(o0 + dd);
    u16x8 bq = *(const u16x8*)(o1 + dd);
    u16x8 ov;
#pragma unroll
    for (int e = 0; e < 8; ++e)
      ov[e] = f2bf(bf2f(a[e]) * s0 + bf2f(bq[e]) * s1);
    *(u16x8*)(dst + dd) = ov;
  }
}

// ---------- launcher ----------

extern "C" void kernel_launch(void* const* d_in, const int* in_sizes, int n_in,
                              void* d_out, int out_size, void* d_ws, size_t ws_size,
                              hipStream_t stream) {
  const float* x     = (const float*)d_in[0];
  const float* w_qkv = (const float*)d_in[1];
  const float* w_out = (const float*)d_in[2];
  float* out = (float*)d_out;

  char* ws = (char*)d_ws;
  unsigned short* xb  = (unsigned short*)(ws);                     // 8 MB  x bf16 (dead after gemm_qkv)
  unsigned short* wqT = (unsigned short*)(ws + (8u << 20));        // 6 MB  w_qkv^T (dead after gemm_qkv)
  unsigned short* woT = (unsigned short*)(ws + (14u << 20));       // 2 MB  w_out^T
  unsigned short* qb  = (unsigned short*)(ws + (16u << 20));       // 8 MB  q (roped, scaled)
  unsigned short* kb  = (unsigned short*)(ws + (24u << 20));       // 8 MB  k (roped)
  unsigned short* vt  = (unsigned short*)(ws + (32u << 20));       // 8 MB  v transposed [32][64][2048]
  unsigned short* ao  = (unsigned short*)(ws + (40u << 20));       // 8 MB  attn out [4096][1024]
  unsigned short* pO  = xb;                                        // partial O bf16 [2048][32][64] (reuse)
  float*          pml = (float*)wqT;                               // partial m/l f32 [2048][64] (reuse)

  cvt_bf16_kernel<<<2048, 256, 0, stream>>>(x, xb, 4096 * 1024);
  transpose_cvt_kernel<<<dim3(96, 32), 256, 0, stream>>>(w_qkv, wqT, 1024, 3072);
  transpose_cvt_kernel<<<dim3(32, 32), 256, 0, stream>>>(w_out, woT, 1024, 1024);
  gemm_tn<0><<<dim3(24, 32), 256, 0, stream>>>(xb, wqT, qb, kb, vt, nullptr, 4096, 3072, 1024);
  attn_fused<<<dim3(96, 32), 64, 0, stream>>>(qb, kb, vt, ao, pO, pml);
  attn_combine<<<1024, 64, 0, stream>>>(pO, pml, ao);
  gemm_tn<1><<<dim3(8, 32), 256, 0, stream>>>(ao, woT, nullptr, nullptr, nullptr, out, 4096, 1024, 1024);
}

// Round 8
// 173.505 us; speedup vs baseline: 1.2582x; 1.1165x over previous
//
#include <hip/hip_runtime.h>
#include <hip/hip_bf16.h>
#include <cstdint>

#define DI __device__ __forceinline__

using u16x8  = __attribute__((ext_vector_type(8))) unsigned short;
using u32x4  = __attribute__((ext_vector_type(4))) unsigned int;
using bf16x8 = __attribute__((ext_vector_type(8))) __bf16;
using f32x4  = __attribute__((ext_vector_type(4))) float;

// ---------- helpers ----------

DI unsigned short f2bf(float f) {           // RNE float -> bf16 bits
  unsigned u = __builtin_bit_cast(unsigned, f);
  u += 0x7fffu + ((u >> 16) & 1u);
  return (unsigned short)(u >> 16);
}
DI float bf2f(unsigned short b) {
  unsigned u = (unsigned)b << 16;
  return __builtin_bit_cast(float, u);
}
DI unsigned cvt_pk_bf16(float lo, float hi) {   // packed {lo,hi} -> 2xbf16 (no builtin on gfx950)
  unsigned r;
  asm("v_cvt_pk_bf16_f32 %0, %1, %2" : "=v"(r) : "v"(lo), "v"(hi));
  return r;
}
// gfx950 cross-lane swaps (both operands read-write):
DI void permlane_swap32(unsigned& a, unsigned& b) {
  asm("v_permlane32_swap_b32 %0, %1" : "+v"(a), "+v"(b));
}
DI void permlane_swap16(unsigned& a, unsigned& b) {
  asm("v_permlane16_swap_b32 %0, %1" : "+v"(a), "+v"(b));
}

DI void gld_lds16(const void* g, void* l) { // async global->LDS, 16B/lane
  __builtin_amdgcn_global_load_lds(
      (const __attribute__((address_space(1))) void*)(uintptr_t)g,
      (__attribute__((address_space(3))) void*)(uint32_t)(uintptr_t)l,
      16, 0, 0);
}

// ---------- conversion kernels ----------

__global__ __launch_bounds__(256) void cvt_bf16_kernel(const float* __restrict__ in,
                                                        unsigned short* __restrict__ out, int n) {
  int i = (blockIdx.x * 256 + threadIdx.x) * 8;
  if (i >= n) return;
  float4 v0 = *(const float4*)(in + i);
  float4 v1 = *(const float4*)(in + i + 4);
  u16x8 o;
  o[0] = f2bf(v0.x); o[1] = f2bf(v0.y); o[2] = f2bf(v0.z); o[3] = f2bf(v0.w);
  o[4] = f2bf(v1.x); o[5] = f2bf(v1.y); o[6] = f2bf(v1.z); o[7] = f2bf(v1.w);
  *(u16x8*)(out + i) = o;
}

// in[K][N] fp32 -> out[N][K] bf16
__global__ __launch_bounds__(256) void transpose_cvt_kernel(const float* __restrict__ in,
                                                             unsigned short* __restrict__ out,
                                                             int K, int N) {
  __shared__ float tile[32][33];
  int n0 = blockIdx.x * 32, k0 = blockIdx.y * 32;
  int tx = threadIdx.x & 31, ty = threadIdx.x >> 5;
#pragma unroll
  for (int i = 0; i < 4; ++i)
    tile[ty * 4 + i][tx] = in[(size_t)(k0 + ty * 4 + i) * N + n0 + tx];
  __syncthreads();
#pragma unroll
  for (int i = 0; i < 4; ++i)
    out[(size_t)(n0 + ty * 4 + i) * K + k0 + tx] = f2bf(tile[tx][ty * 4 + i]);
}

// ---------- TN GEMM: C[M,N] = A[M,K] * B[N,K]^T  (bf16 inputs, fp32 acc) ----------
// MODE 0: epilogue: RoPE; q scaled by 0.125*log2e (exp2-domain softmax); v stored transposed.
// MODE 1: plain fp32 store.

template <int MODE>
__global__ __launch_bounds__(256)
void gemm_tn(const unsigned short* __restrict__ A, const unsigned short* __restrict__ B,
             unsigned short* __restrict__ q_out, unsigned short* __restrict__ k_out,
             unsigned short* __restrict__ v_out, float* __restrict__ c_out,
             int M, int N, int K) {
  __shared__ __align__(16) char smem[2][16384];
  const int tid = threadIdx.x;
  const int lane = tid & 63, wave = tid >> 6;
  const int wm = wave >> 1, wn = wave & 1;
  const int m0 = blockIdx.y << 7, n0 = blockIdx.x << 7;
  const int r15 = lane & 15, g4 = lane >> 4;

  const size_t Ks = (size_t)K;
  const unsigned short* aptr = A + (size_t)(m0 + wave * 16 + r15) * Ks + g4 * 8;
  const unsigned short* bptr = B + (size_t)(n0 + wave * 16 + r15) * Ks + g4 * 8;

  f32x4 acc[4][4] = {};
  const int NT = K >> 5;

  auto stage = [&](int buf, int kt) {
    const unsigned short* ak = aptr + kt * 32;
    const unsigned short* bk = bptr + kt * 32;
    char* sA = &smem[buf][0] + wave * 1024;
    char* sB = &smem[buf][8192] + wave * 1024;
    gld_lds16(ak, sA);
    gld_lds16(ak + 64 * Ks, sA + 4096);
    gld_lds16(bk, sB);
    gld_lds16(bk + 64 * Ks, sB + 4096);
  };

  stage(0, 0);
  __syncthreads();
  for (int kt = 0; kt < NT; ++kt) {
    int buf = kt & 1;
    if (kt + 1 < NT) stage(buf ^ 1, kt + 1);
    const char* base = &smem[buf][0];
    bf16x8 af[4], bfr[4];
#pragma unroll
    for (int mt = 0; mt < 4; ++mt)
      af[mt] = *(const bf16x8*)(base + ((wm * 4 + mt) * 64 + lane) * 16);
#pragma unroll
    for (int nt = 0; nt < 4; ++nt)
      bfr[nt] = *(const bf16x8*)(base + 8192 + ((wn * 4 + nt) * 64 + lane) * 16);
#pragma unroll
    for (int mt = 0; mt < 4; ++mt)
#pragma unroll
      for (int nt = 0; nt < 4; ++nt)
        acc[mt][nt] = __builtin_amdgcn_mfma_f32_16x16x32_bf16(af[mt], bfr[nt], acc[mt][nt], 0, 0, 0);
    __syncthreads();
  }

  const int gm0 = m0 + wm * 64, gn0 = n0 + wn * 64;
  if constexpr (MODE == 0) {
    const int region = gn0 >> 10;               // 0=q 1=k 2=v
    const int h = (gn0 & 1023) >> 6;
    if (region <= 1) {
      unsigned short* dst = (region == 0) ? q_out : k_out;
      const float qs = (region == 0) ? (0.125f * 1.44269504088896341f) : 1.0f;
#pragma unroll
      for (int mt = 0; mt < 4; ++mt) {
#pragma unroll
        for (int r = 0; r < 4; ++r) {
          int mrow = gm0 + mt * 16 + g4 * 4 + r;
          int b = mrow >> 11, t = mrow & 2047;
          unsigned short* rowp = dst + (((size_t)(b * 16 + h) * 2048 + t) << 6);
          float tf = (float)t;
#pragma unroll
          for (int nt = 0; nt < 2; ++nt) {
            int j = nt * 16 + r15;
            float invf = exp2f((float)j * -0.4152410118609203f);  // 10000^(-j/32)
            float ang = tf * invf;
            float sv, cv;
            sincosf(ang, &sv, &cv);
            float x1 = acc[mt][nt][r], x2 = acc[mt][nt + 2][r];
            rowp[j]      = f2bf((x1 * cv - x2 * sv) * qs);
            rowp[j + 32] = f2bf((x2 * cv + x1 * sv) * qs);
          }
        }
      }
    } else {                                    // v -> transposed [BH][64][T]
#pragma unroll
      for (int mt = 0; mt < 4; ++mt)
#pragma unroll
        for (int r = 0; r < 4; ++r) {
          int mrow = gm0 + mt * 16 + g4 * 4 + r;
          int b = mrow >> 11, t = mrow & 2047;
          unsigned short* colp = v_out + ((size_t)(b * 16 + h) * 64) * 2048 + t;
#pragma unroll
          for (int nt = 0; nt < 4; ++nt)
            colp[(size_t)(nt * 16 + r15) * 2048] = f2bf(acc[mt][nt][r]);
        }
    }
  } else {
#pragma unroll
    for (int mt = 0; mt < 4; ++mt)
#pragma unroll
      for (int r = 0; r < 4; ++r) {
        int mrow = gm0 + mt * 16 + g4 * 4 + r;
        float* rowp = c_out + (size_t)mrow * N + gn0;
#pragma unroll
        for (int nt = 0; nt < 4; ++nt)
          rowp[nt * 16 + r15] = acc[mt][nt][r];
      }
  }
}

// ---------- causal flash attention, v5 ----------
// 4-wave blocks, QBLK=128 (32 q-rows/wave). K and V^T tiles shared across waves,
// double-buffered in LDS (frag-order via global_load_lds; conflict-free ds_read_b128).
// Per-wave: swapped QK^T -> in-register softmax -> cvt_pk+permlane repack -> PV
// (verified machinery from v4, unchanged). Balanced kv-split: J<8 one chunk,
// J>=8 two chunks of J+1 tiles each (chunk 0 mask-free). XCD-swizzled block ids.

__global__ __launch_bounds__(256)
void attn_fused(const unsigned short* __restrict__ qb, const unsigned short* __restrict__ kb,
                const unsigned short* __restrict__ vt, unsigned short* __restrict__ attno,
                unsigned short* __restrict__ pO, float* __restrict__ pml) {
  __shared__ __align__(16) char ksm[2][8192];
  __shared__ __align__(16) char vsm[2][8192];

  const int tid = threadIdx.x, lane = tid & 63, wave = tid >> 6;
  const int r15 = lane & 15, g4 = lane >> 4;

  // bijective XCD swizzle: 768 = 8 * 96; XCD x hosts swz in [96x, 96x+96) = bh [4x, 4x+4)
  const int wg = blockIdx.x;                  // 0..767
  const int swz = (wg & 7) * 96 + (wg >> 3);
  const int bh = swz / 24;
  const int rb = swz % 24;                    // 0..23 within bh
  int J, c; bool multi;
  if (rb < 8) { J = rb; c = 0; multi = false; }
  else { int rr = rb - 8; J = 8 + (rr >> 1); c = rr & 1; multi = true; }
  const int ntw = 2 * J + 2;                  // kv tiles for this q-block
  const int ktmid = J + 1;                    // balanced split point (chunk sizes J+1, J+1)
  const int kt0 = (multi && c) ? ktmid : 0;
  const int ktN = multi ? (c ? ntw : ktmid) : ntw;
  const int q0 = J << 7;
  const int q0w = q0 + wave * 32;

  const size_t hb = (size_t)bh * 2048 * 64;
  const unsigned short* Qp = qb + hb;
  const unsigned short* Kp = kb + hb;
  const unsigned short* Vp = vt + hb;         // [64][2048]

  bf16x8 qf[2][2];
#pragma unroll
  for (int mq = 0; mq < 2; ++mq)
#pragma unroll
    for (int kc = 0; kc < 2; ++kc)
      qf[mq][kc] = *(const bf16x8*)(Qp + (size_t)(q0w + mq * 16 + r15) * 64 + kc * 32 + g4 * 8);

  f32x4 o[2][4] = {};
  float mr[2] = {-INFINITY, -INFINITY};
  float lr[2] = {0.f, 0.f};

  // cooperative staging: wave covers frags {2*wave, 2*wave+1} of K and V
  auto stage = [&](int buf, int kt) {
    const int kv0 = kt << 6;
#pragma unroll
    for (int i = 0; i < 2; ++i) {
      int f = wave * 2 + i;
      int nt = f >> 1, kc = f & 1;
      gld_lds16(Kp + (size_t)(kv0 + nt * 16 + r15) * 64 + kc * 32 + g4 * 8, &ksm[buf][f * 1024]);
      gld_lds16(Vp + (size_t)(nt * 16 + r15) * 2048 + kv0 + kc * 32 + g4 * 8, &vsm[buf][f * 1024]);
    }
  };

  auto process = [&](int buf, int kv0, bool mask) {
    bf16x8 kf[8];
#pragma unroll
    for (int i = 0; i < 8; ++i)
      kf[i] = *(const bf16x8*)(&ksm[buf][i * 1024] + lane * 16);

    f32x4 s[4][2] = {};                       // [nt][mq]: row kv = 16nt+4g4+r, col q = 16mq+r15
    __builtin_amdgcn_s_setprio(1);
#pragma unroll
    for (int nt = 0; nt < 4; ++nt)
#pragma unroll
      for (int kc = 0; kc < 2; ++kc) {
        s[nt][0] = __builtin_amdgcn_mfma_f32_16x16x32_bf16(kf[nt * 2 + kc], qf[0][kc], s[nt][0], 0, 0, 0);
        s[nt][1] = __builtin_amdgcn_mfma_f32_16x16x32_bf16(kf[nt * 2 + kc], qf[1][kc], s[nt][1], 0, 0, 0);
      }
    __builtin_amdgcn_s_setprio(0);

    if (mask) {
#pragma unroll
      for (int nt = 0; nt < 4; ++nt)
#pragma unroll
        for (int mq = 0; mq < 2; ++mq)
#pragma unroll
          for (int r = 0; r < 4; ++r)
            if (kv0 + nt * 16 + g4 * 4 + r > q0w + mq * 16 + r15) s[nt][mq][r] = -1e9f;
    }

    bf16x8 pa[2][2];                          // A-frag for PV: [mq][kc]
#pragma unroll
    for (int mq = 0; mq < 2; ++mq) {
      float m0 = fmaxf(fmaxf(s[0][mq][0], s[0][mq][1]), fmaxf(s[0][mq][2], s[0][mq][3]));
      float m1 = fmaxf(fmaxf(s[1][mq][0], s[1][mq][1]), fmaxf(s[1][mq][2], s[1][mq][3]));
      float m2 = fmaxf(fmaxf(s[2][mq][0], s[2][mq][1]), fmaxf(s[2][mq][2], s[2][mq][3]));
      float m3 = fmaxf(fmaxf(s[3][mq][0], s[3][mq][1]), fmaxf(s[3][mq][2], s[3][mq][3]));
      float mx = fmaxf(fmaxf(m0, m1), fmaxf(m2, m3));
      mx = fmaxf(mx, __shfl_xor(mx, 16));
      mx = fmaxf(mx, __shfl_xor(mx, 32));
      float mnew = fmaxf(mr[mq], mx);
      float fsc = exp2f(mr[mq] - mnew);
      mr[mq] = mnew;
      float t0 = 0.f, t1 = 0.f, t2 = 0.f, t3 = 0.f;
#pragma unroll
      for (int nt = 0; nt < 4; ++nt) {
        float p0 = exp2f(s[nt][mq][0] - mnew);
        float p1 = exp2f(s[nt][mq][1] - mnew);
        float p2 = exp2f(s[nt][mq][2] - mnew);
        float p3 = exp2f(s[nt][mq][3] - mnew);
        s[nt][mq][0] = p0; s[nt][mq][1] = p1; s[nt][mq][2] = p2; s[nt][mq][3] = p3;
        if (nt == 0) t0 = (p0 + p1) + (p2 + p3);
        if (nt == 1) t1 = (p0 + p1) + (p2 + p3);
        if (nt == 2) t2 = (p0 + p1) + (p2 + p3);
        if (nt == 3) t3 = (p0 + p1) + (p2 + p3);
      }
      float ps = (t0 + t1) + (t2 + t3);
      ps += __shfl_xor(ps, 16);
      ps += __shfl_xor(ps, 32);
      lr[mq] = lr[mq] * fsc + ps;
#pragma unroll
      for (int r = 0; r < 4; ++r) {
        float fr = __shfl(fsc, (g4 << 2) + r);
#pragma unroll
        for (int dt = 0; dt < 4; ++dt) o[mq][dt][r] *= fr;
      }
      unsigned p32[4][2];
#pragma unroll
      for (int nt = 0; nt < 4; ++nt) {
        p32[nt][0] = cvt_pk_bf16(s[nt][mq][0], s[nt][mq][1]);
        p32[nt][1] = cvt_pk_bf16(s[nt][mq][2], s[nt][mq][3]);
      }
#pragma unroll
      for (int kc = 0; kc < 2; ++kc) {
        u32x4 w;
#pragma unroll
        for (int pi = 0; pi < 2; ++pi) {
          unsigned a = p32[2 * kc][pi], b = p32[2 * kc + 1][pi];
          permlane_swap32(a, b);
          permlane_swap16(a, b);
          w[pi] = a;
          w[2 + pi] = b;
        }
        pa[mq][kc] = __builtin_bit_cast(bf16x8, w);
      }
    }

    bf16x8 vf[8];
#pragma unroll
    for (int i = 0; i < 8; ++i)
      vf[i] = *(const bf16x8*)(&vsm[buf][i * 1024] + lane * 16);

    __builtin_amdgcn_s_setprio(1);
#pragma unroll
    for (int kc = 0; kc < 2; ++kc)
#pragma unroll
      for (int dt = 0; dt < 4; ++dt) {
        o[0][dt] = __builtin_amdgcn_mfma_f32_16x16x32_bf16(pa[0][kc], vf[dt * 2 + kc], o[0][dt], 0, 0, 0);
        o[1][dt] = __builtin_amdgcn_mfma_f32_16x16x32_bf16(pa[1][kc], vf[dt * 2 + kc], o[1][dt], 0, 0, 0);
      }
    __builtin_amdgcn_s_setprio(0);
  };

  int buf = 0;
  stage(0, kt0);
  __syncthreads();
  for (int kt = kt0; kt < ktN; ++kt) {
    if (kt + 1 < ktN) stage(buf ^ 1, kt + 1);
    const int kv0 = kt << 6;
    if (kv0 <= q0w + 31)                       // wave-uniform causal skip
      process(buf, kv0, kv0 + 63 > q0w);
    __syncthreads();                           // drains vmcnt (next buf ready) + all reads of buf done
    buf ^= 1;
  }

  if (!multi) {
    const int b = bh >> 4, h = bh & 15;
#pragma unroll
    for (int mq = 0; mq < 2; ++mq) {
      float inv = 1.f / lr[mq];
#pragma unroll
      for (int r = 0; r < 4; ++r) {
        float ir = __shfl(inv, (g4 << 2) + r);
        int q = q0w + mq * 16 + g4 * 4 + r;
        unsigned short* rowp = attno + (size_t)(b * 2048 + q) * 1024 + h * 64;
#pragma unroll
        for (int dt = 0; dt < 4; ++dt)
          rowp[dt * 16 + r15] = f2bf(o[mq][dt][r] * ir);
      }
    }
  } else {
    const int sidx = (bh * 8 + (J - 8)) * 2 + c;
    unsigned short* po = pO + (size_t)sidx * 8192 + wave * 32 * 64;
#pragma unroll
    for (int mq = 0; mq < 2; ++mq)
#pragma unroll
      for (int r = 0; r < 4; ++r)
#pragma unroll
        for (int dt = 0; dt < 4; ++dt)
          po[(mq * 16 + g4 * 4 + r) * 64 + dt * 16 + r15] = f2bf(o[mq][dt][r]);
    if (g4 == 0) {
      float* pm = pml + sidx * 256 + wave * 32;
#pragma unroll
      for (int mq = 0; mq < 2; ++mq) {
        pm[mq * 16 + r15] = mr[mq];
        pm[128 + mq * 16 + r15] = lr[mq];
      }
    }
  }
}

// ---------- combine partials for q-blocks J>=8 (2 chunks each) ----------
__global__ __launch_bounds__(256)
void attn_combine(const unsigned short* __restrict__ pO, const float* __restrict__ pml,
                  unsigned short* __restrict__ attno) {
  const int bx = blockIdx.x;                 // 0..255 = 32 bh x 8 Jrel
  const int bh = bx >> 3, Jrel = bx & 7, J = 8 + Jrel;
  const int t = threadIdx.x;                 // 0..255
  const int row = t >> 1;                    // 0..127
  const int dh = (t & 1) << 5;               // 0 or 32
  const int s0i = (bh * 8 + Jrel) * 2;
  const float* pm0 = pml + s0i * 256;
  const float* pm1 = pm0 + 256;
  float m0 = pm0[row], l0 = pm0[128 + row];
  float m1 = pm1[row], l1 = pm1[128 + row];
  float mg = fmaxf(m0, m1);
  float s0 = exp2f(m0 - mg), s1 = exp2f(m1 - mg);
  float inv = 1.f / (l0 * s0 + l1 * s1);
  s0 *= inv; s1 *= inv;
  const unsigned short* o0 = pO + (size_t)s0i * 8192 + row * 64 + dh;
  const unsigned short* o1 = o0 + 8192;
  const int b = bh >> 4, h = bh & 15;
  const int q = J * 128 + row;
  unsigned short* dst = attno + (size_t)(b * 2048 + q) * 1024 + h * 64 + dh;
#pragma unroll
  for (int dd = 0; dd < 32; dd += 8) {
    u16x8 a = *(const u16x8*)(o0 + dd);
    u16x8 bq = *(const u16x8*)(o1 + dd);
    u16x8 ov;
#pragma unroll
    for (int e = 0; e < 8; ++e)
      ov[e] = f2bf(bf2f(a[e]) * s0 + bf2f(bq[e]) * s1);
    *(u16x8*)(dst + dd) = ov;
  }
}

// ---------- launcher ----------

extern "C" void kernel_launch(void* const* d_in, const int* in_sizes, int n_in,
                              void* d_out, int out_size, void* d_ws, size_t ws_size,
                              hipStream_t stream) {
  const float* x     = (const float*)d_in[0];
  const float* w_qkv = (const float*)d_in[1];
  const float* w_out = (const float*)d_in[2];
  float* out = (float*)d_out;

  char* ws = (char*)d_ws;
  unsigned short* xb  = (unsigned short*)(ws);                     // 8 MB  x bf16 (dead after gemm_qkv)
  unsigned short* wqT = (unsigned short*)(ws + (8u << 20));        // 6 MB  w_qkv^T (dead after gemm_qkv)
  unsigned short* woT = (unsigned short*)(ws + (14u << 20));       // 2 MB  w_out^T
  unsigned short* qb  = (unsigned short*)(ws + (16u << 20));       // 8 MB  q (roped, scaled)
  unsigned short* kb  = (unsigned short*)(ws + (24u << 20));       // 8 MB  k (roped)
  unsigned short* vt  = (unsigned short*)(ws + (32u << 20));       // 8 MB  v transposed [32][64][2048]
  unsigned short* ao  = (unsigned short*)(ws + (40u << 20));       // 8 MB  attn out [4096][1024]
  unsigned short* pO  = xb;                                        // partial O bf16 [512][128][64] (8 MB, reuse)
  float*          pml = (float*)wqT;                               // partial m/l f32 [512][256] (512 KB, reuse)

  cvt_bf16_kernel<<<2048, 256, 0, stream>>>(x, xb, 4096 * 1024);
  transpose_cvt_kernel<<<dim3(96, 32), 256, 0, stream>>>(w_qkv, wqT, 1024, 3072);
  transpose_cvt_kernel<<<dim3(32, 32), 256, 0, stream>>>(w_out, woT, 1024, 1024);
  gemm_tn<0><<<dim3(24, 32), 256, 0, stream>>>(xb, wqT, qb, kb, vt, nullptr, 4096, 3072, 1024);
  attn_fused<<<768, 256, 0, stream>>>(qb, kb, vt, ao, pO, pml);
  attn_combine<<<256, 256, 0, stream>>>(pO, pml, ao);
  gemm_tn<1><<<dim3(8, 32), 256, 0, stream>>>(ao, woT, nullptr, nullptr, nullptr, out, 4096, 1024, 1024);
}

// Round 9
// 159.098 us; speedup vs baseline: 1.3721x; 1.0906x over previous
//
#include <hip/hip_runtime.h>
#include <hip/hip_bf16.h>
#include <cstdint>

#define DI __device__ __forceinline__

using u16x8  = __attribute__((ext_vector_type(8))) unsigned short;
using u32x4  = __attribute__((ext_vector_type(4))) unsigned int;
using bf16x8 = __attribute__((ext_vector_type(8))) __bf16;
using f32x4  = __attribute__((ext_vector_type(4))) float;

// ---------- helpers ----------

DI unsigned short f2bf(float f) {           // RNE float -> bf16 bits
  unsigned u = __builtin_bit_cast(unsigned, f);
  u += 0x7fffu + ((u >> 16) & 1u);
  return (unsigned short)(u >> 16);
}
DI float bf2f(unsigned short b) {
  unsigned u = (unsigned)b << 16;
  return __builtin_bit_cast(float, u);
}
DI unsigned cvt_pk_bf16(float lo, float hi) {   // packed {lo,hi} -> 2xbf16 (no builtin on gfx950)
  unsigned r;
  asm("v_cvt_pk_bf16_f32 %0, %1, %2" : "=v"(r) : "v"(lo), "v"(hi));
  return r;
}
// gfx950 cross-lane swaps (both operands read-write):
DI void permlane_swap32(unsigned& a, unsigned& b) {
  asm("v_permlane32_swap_b32 %0, %1" : "+v"(a), "+v"(b));
}
DI void permlane_swap16(unsigned& a, unsigned& b) {
  asm("v_permlane16_swap_b32 %0, %1" : "+v"(a), "+v"(b));
}

DI void gld_lds16(const void* g, void* l) { // async global->LDS, 16B/lane
  __builtin_amdgcn_global_load_lds(
      (const __attribute__((address_space(1))) void*)(uintptr_t)g,
      (__attribute__((address_space(3))) void*)(uint32_t)(uintptr_t)l,
      16, 0, 0);
}

// ---------- conversion kernels ----------

__global__ __launch_bounds__(256) void cvt_bf16_kernel(const float* __restrict__ in,
                                                        unsigned short* __restrict__ out, int n) {
  int i = (blockIdx.x * 256 + threadIdx.x) * 8;
  if (i >= n) return;
  float4 v0 = *(const float4*)(in + i);
  float4 v1 = *(const float4*)(in + i + 4);
  u16x8 o;
  o[0] = f2bf(v0.x); o[1] = f2bf(v0.y); o[2] = f2bf(v0.z); o[3] = f2bf(v0.w);
  o[4] = f2bf(v1.x); o[5] = f2bf(v1.y); o[6] = f2bf(v1.z); o[7] = f2bf(v1.w);
  *(u16x8*)(out + i) = o;
}

// in[K][N] fp32 -> out[N][K] bf16
__global__ __launch_bounds__(256) void transpose_cvt_kernel(const float* __restrict__ in,
                                                             unsigned short* __restrict__ out,
                                                             int K, int N) {
  __shared__ float tile[32][33];
  int n0 = blockIdx.x * 32, k0 = blockIdx.y * 32;
  int tx = threadIdx.x & 31, ty = threadIdx.x >> 5;
#pragma unroll
  for (int i = 0; i < 4; ++i)
    tile[ty * 4 + i][tx] = in[(size_t)(k0 + ty * 4 + i) * N + n0 + tx];
  __syncthreads();
#pragma unroll
  for (int i = 0; i < 4; ++i)
    out[(size_t)(n0 + ty * 4 + i) * K + k0 + tx] = f2bf(tile[tx][ty * 4 + i]);
}

// ---------- TN GEMM: C[M,N] = A[M,K] * B[N,K]^T  (bf16 inputs, fp32 acc) ----------
// 1-D grid, XCD band swizzle: XCD k owns n-tiles [k*bandw, (k+1)*bandw) -> B panels L2-resident.
// MODE 0: epilogue: RoPE; q scaled by 0.125*log2e; v transposed via LDS (coalesced stores).
// MODE 1: plain fp32 store.

template <int MODE>
__global__ __launch_bounds__(256)
void gemm_tn(const unsigned short* __restrict__ A, const unsigned short* __restrict__ B,
             unsigned short* __restrict__ q_out, unsigned short* __restrict__ k_out,
             unsigned short* __restrict__ v_out, float* __restrict__ c_out,
             int M, int N, int K) {
  __shared__ __align__(16) char smem[2][16384];
  const int tid = threadIdx.x;
  const int lane = tid & 63, wave = tid >> 6;
  const int wm = wave >> 1, wn = wave & 1;

  constexpr int BANDW = (MODE == 0) ? 3 : 1;    // n-tiles per XCD band (24 or 8 total)
  const int id = blockIdx.x;
  const int xcd = id & 7, rr = id >> 3;
  const int bx = xcd * BANDW + rr % BANDW;
  const int by = rr / BANDW;
  const int m0 = by << 7, n0 = bx << 7;

  const int r15 = lane & 15, g4 = lane >> 4;

  const size_t Ks = (size_t)K;
  const unsigned short* aptr = A + (size_t)(m0 + wave * 16 + r15) * Ks + g4 * 8;
  const unsigned short* bptr = B + (size_t)(n0 + wave * 16 + r15) * Ks + g4 * 8;

  f32x4 acc[4][4] = {};
  const int NT = K >> 5;

  auto stage = [&](int buf, int kt) {
    const unsigned short* ak = aptr + kt * 32;
    const unsigned short* bk = bptr + kt * 32;
    char* sA = &smem[buf][0] + wave * 1024;
    char* sB = &smem[buf][8192] + wave * 1024;
    gld_lds16(ak, sA);
    gld_lds16(ak + 64 * Ks, sA + 4096);
    gld_lds16(bk, sB);
    gld_lds16(bk + 64 * Ks, sB + 4096);
  };

  stage(0, 0);
  __syncthreads();
  for (int kt = 0; kt < NT; ++kt) {
    int buf = kt & 1;
    if (kt + 1 < NT) stage(buf ^ 1, kt + 1);
    const char* base = &smem[buf][0];
    bf16x8 af[4], bfr[4];
#pragma unroll
    for (int mt = 0; mt < 4; ++mt)
      af[mt] = *(const bf16x8*)(base + ((wm * 4 + mt) * 64 + lane) * 16);
#pragma unroll
    for (int nt = 0; nt < 4; ++nt)
      bfr[nt] = *(const bf16x8*)(base + 8192 + ((wn * 4 + nt) * 64 + lane) * 16);
#pragma unroll
    for (int mt = 0; mt < 4; ++mt)
#pragma unroll
      for (int nt = 0; nt < 4; ++nt)
        acc[mt][nt] = __builtin_amdgcn_mfma_f32_16x16x32_bf16(af[mt], bfr[nt], acc[mt][nt], 0, 0, 0);
    __syncthreads();
  }

  const int gm0 = m0 + wm * 64, gn0 = n0 + wn * 64;
  if constexpr (MODE == 0) {
    const int region = gn0 >> 10;               // 0=q 1=k 2=v
    const int h = (gn0 & 1023) >> 6;
    if (region <= 1) {
      unsigned short* dst = (region == 0) ? q_out : k_out;
      const float qs = (region == 0) ? (0.125f * 1.44269504088896341f) : 1.0f;
#pragma unroll
      for (int mt = 0; mt < 4; ++mt) {
#pragma unroll
        for (int r = 0; r < 4; ++r) {
          int mrow = gm0 + mt * 16 + g4 * 4 + r;
          int b = mrow >> 11, t = mrow & 2047;
          unsigned short* rowp = dst + (((size_t)(b * 16 + h) * 2048 + t) << 6);
          float tf = (float)t;
#pragma unroll
          for (int nt = 0; nt < 2; ++nt) {
            int j = nt * 16 + r15;
            float invf = exp2f((float)j * -0.4152410118609203f);  // 10000^(-j/32)
            float ang = tf * invf;
            float sv, cv;
            sincosf(ang, &sv, &cv);
            float x1 = acc[mt][nt][r], x2 = acc[mt][nt + 2][r];
            rowp[j]      = f2bf((x1 * cv - x2 * sv) * qs);
            rowp[j + 32] = f2bf((x2 * cv + x1 * sv) * qs);
          }
        }
      }
    } else {
      // v -> transposed [BH][64][T] via wave-private LDS transpose (smem free after K-loop).
      // Two passes of 32 d-rows: [32][72] shorts (stride 144 B keeps 16B-aligned b128 reads).
      const int b = gm0 >> 11, t0 = gm0 & 2047;   // 64-row tile never crosses the 2048 boundary
      unsigned short* vhead = v_out + ((size_t)(b * 16 + h) * 64) * 2048;
      short* tb = (short*)(&smem[0][0] + wave * 8192);
#pragma unroll
      for (int p = 0; p < 2; ++p) {
#pragma unroll
        for (int np = 0; np < 2; ++np)
#pragma unroll
          for (int mt = 0; mt < 4; ++mt)
#pragma unroll
            for (int pr = 0; pr < 2; ++pr) {
              unsigned pk = cvt_pk_bf16(acc[mt][2 * p + np][2 * pr], acc[mt][2 * p + np][2 * pr + 1]);
              *(unsigned*)(tb + (np * 16 + r15) * 72 + mt * 16 + g4 * 4 + pr * 2) = pk;
            }
        // read back d-rows, store coalesced (8 lanes = one 128B row segment)
#pragma unroll
        for (int cc = 0; cc < 4; ++cc) {
          int dl = cc * 8 + (lane >> 3);
          int tc = (lane & 7) * 8;
          u16x8 vv = *(const u16x8*)(tb + dl * 72 + tc);
          *(u16x8*)(vhead + (size_t)(p * 32 + dl) * 2048 + t0 + tc) = vv;
        }
      }
    }
  } else {
#pragma unroll
    for (int mt = 0; mt < 4; ++mt)
#pragma unroll
      for (int r = 0; r < 4; ++r) {
        int mrow = gm0 + mt * 16 + g4 * 4 + r;
        float* rowp = c_out + (size_t)mrow * N + gn0;
#pragma unroll
        for (int nt = 0; nt < 4; ++nt)
          rowp[nt * 16 + r15] = acc[mt][nt][r];
      }
  }
}

// ---------- causal flash attention, v6 ----------
// v5 structure (4-wave blocks, QBLK=128, LDS-shared double-buffered K/V tiles, swapped
// QK^T + in-register softmax + cvt_pk/permlane repack) plus:
//  - T13 defer-max: skip O-rescale when __all(mx <= m+8)  (exp2 domain, P <= 256)
//  - LPT slot packing: CU c hosts work-slots {c, c+8, c+16 mod 24}; RBMAP makes every
//    such triple sum to 32-35 tiles (was 24-44) -> smaller tail.

__device__ const int RBMAP[24] = {7, 23, 20, 21, 18, 19, 17, 5,
                                  22, 6, 16, 12, 13, 14, 15, 10,
                                  0, 1, 2, 3, 8, 9, 4, 11};

__global__ __launch_bounds__(256)
void attn_fused(const unsigned short* __restrict__ qb, const unsigned short* __restrict__ kb,
                const unsigned short* __restrict__ vt, unsigned short* __restrict__ attno,
                unsigned short* __restrict__ pO, float* __restrict__ pml) {
  __shared__ __align__(16) char ksm[2][8192];
  __shared__ __align__(16) char vsm[2][8192];

  const int tid = threadIdx.x, lane = tid & 63, wave = tid >> 6;
  const int r15 = lane & 15, g4 = lane >> 4;

  // XCD x hosts bh [4x, 4x+4); per-XCD dispatch order is bh-major, slot-minor.
  const int wg = blockIdx.x;                  // 0..767
  const int qq = wg >> 3;                     // 0..95
  const int bh = (wg & 7) * 4 + qq / 24;
  const int rb = RBMAP[qq % 24];
  int J, c; bool multi;
  if (rb < 8) { J = rb; c = 0; multi = false; }
  else { int rr = rb - 8; J = 8 + (rr >> 1); c = rr & 1; multi = true; }
  const int ntw = 2 * J + 2;                  // kv tiles for this q-block
  const int ktmid = J + 1;                    // balanced split (J+1, J+1)
  const int kt0 = (multi && c) ? ktmid : 0;
  const int ktN = multi ? (c ? ntw : ktmid) : ntw;
  const int q0 = J << 7;
  const int q0w = q0 + wave * 32;

  const size_t hb = (size_t)bh * 2048 * 64;
  const unsigned short* Qp = qb + hb;
  const unsigned short* Kp = kb + hb;
  const unsigned short* Vp = vt + hb;         // [64][2048]

  bf16x8 qf[2][2];
#pragma unroll
  for (int mq = 0; mq < 2; ++mq)
#pragma unroll
    for (int kc = 0; kc < 2; ++kc)
      qf[mq][kc] = *(const bf16x8*)(Qp + (size_t)(q0w + mq * 16 + r15) * 64 + kc * 32 + g4 * 8);

  f32x4 o[2][4] = {};
  float mr[2] = {-INFINITY, -INFINITY};
  float lr[2] = {0.f, 0.f};

  auto stage = [&](int buf, int kt) {
    const int kv0 = kt << 6;
#pragma unroll
    for (int i = 0; i < 2; ++i) {
      int f = wave * 2 + i;
      int nt = f >> 1, kc = f & 1;
      gld_lds16(Kp + (size_t)(kv0 + nt * 16 + r15) * 64 + kc * 32 + g4 * 8, &ksm[buf][f * 1024]);
      gld_lds16(Vp + (size_t)(nt * 16 + r15) * 2048 + kv0 + kc * 32 + g4 * 8, &vsm[buf][f * 1024]);
    }
  };

  auto process = [&](int buf, int kv0, bool mask) {
    bf16x8 kf[8];
#pragma unroll
    for (int i = 0; i < 8; ++i)
      kf[i] = *(const bf16x8*)(&ksm[buf][i * 1024] + lane * 16);

    f32x4 s[4][2] = {};                       // [nt][mq]: row kv = 16nt+4g4+r, col q = 16mq+r15
    __builtin_amdgcn_s_setprio(1);
#pragma unroll
    for (int nt = 0; nt < 4; ++nt)
#pragma unroll
      for (int kc = 0; kc < 2; ++kc) {
        s[nt][0] = __builtin_amdgcn_mfma_f32_16x16x32_bf16(kf[nt * 2 + kc], qf[0][kc], s[nt][0], 0, 0, 0);
        s[nt][1] = __builtin_amdgcn_mfma_f32_16x16x32_bf16(kf[nt * 2 + kc], qf[1][kc], s[nt][1], 0, 0, 0);
      }
    __builtin_amdgcn_s_setprio(0);

    if (mask) {
#pragma unroll
      for (int nt = 0; nt < 4; ++nt)
#pragma unroll
        for (int mq = 0; mq < 2; ++mq)
#pragma unroll
          for (int r = 0; r < 4; ++r)
            if (kv0 + nt * 16 + g4 * 4 + r > q0w + mq * 16 + r15) s[nt][mq][r] = -1e9f;
    }

    bf16x8 pa[2][2];                          // A-frag for PV: [mq][kc]
#pragma unroll
    for (int mq = 0; mq < 2; ++mq) {
      float m0 = fmaxf(fmaxf(s[0][mq][0], s[0][mq][1]), fmaxf(s[0][mq][2], s[0][mq][3]));
      float m1 = fmaxf(fmaxf(s[1][mq][0], s[1][mq][1]), fmaxf(s[1][mq][2], s[1][mq][3]));
      float m2 = fmaxf(fmaxf(s[2][mq][0], s[2][mq][1]), fmaxf(s[2][mq][2], s[2][mq][3]));
      float m3 = fmaxf(fmaxf(s[3][mq][0], s[3][mq][1]), fmaxf(s[3][mq][2], s[3][mq][3]));
      float mx = fmaxf(fmaxf(m0, m1), fmaxf(m2, m3));
      mx = fmaxf(mx, __shfl_xor(mx, 16));
      mx = fmaxf(mx, __shfl_xor(mx, 32));
      // T13 defer-max: rescale only when a row grew by > 8 (exp2 domain; P <= 2^8)
      float mnew;
      if (!__all(mx <= mr[mq] + 8.f)) {
        mnew = fmaxf(mr[mq], mx);
        float fsc = exp2f(mr[mq] - mnew);
        mr[mq] = mnew;
        lr[mq] *= fsc;
#pragma unroll
        for (int r = 0; r < 4; ++r) {
          float fr = __shfl(fsc, (g4 << 2) + r);
#pragma unroll
          for (int dt = 0; dt < 4; ++dt) o[mq][dt][r] *= fr;
        }
      } else {
        mnew = mr[mq];
      }
      float t0 = 0.f, t1 = 0.f, t2 = 0.f, t3 = 0.f;
#pragma unroll
      for (int nt = 0; nt < 4; ++nt) {
        float p0 = exp2f(s[nt][mq][0] - mnew);
        float p1 = exp2f(s[nt][mq][1] - mnew);
        float p2 = exp2f(s[nt][mq][2] - mnew);
        float p3 = exp2f(s[nt][mq][3] - mnew);
        s[nt][mq][0] = p0; s[nt][mq][1] = p1; s[nt][mq][2] = p2; s[nt][mq][3] = p3;
        if (nt == 0) t0 = (p0 + p1) + (p2 + p3);
        if (nt == 1) t1 = (p0 + p1) + (p2 + p3);
        if (nt == 2) t2 = (p0 + p1) + (p2 + p3);
        if (nt == 3) t3 = (p0 + p1) + (p2 + p3);
      }
      float ps = (t0 + t1) + (t2 + t3);
      ps += __shfl_xor(ps, 16);
      ps += __shfl_xor(ps, 32);
      lr[mq] += ps;
      unsigned p32[4][2];
#pragma unroll
      for (int nt = 0; nt < 4; ++nt) {
        p32[nt][0] = cvt_pk_bf16(s[nt][mq][0], s[nt][mq][1]);
        p32[nt][1] = cvt_pk_bf16(s[nt][mq][2], s[nt][mq][3]);
      }
#pragma unroll
      for (int kc = 0; kc < 2; ++kc) {
        u32x4 w;
#pragma unroll
        for (int pi = 0; pi < 2; ++pi) {
          unsigned a = p32[2 * kc][pi], b = p32[2 * kc + 1][pi];
          permlane_swap32(a, b);
          permlane_swap16(a, b);
          w[pi] = a;
          w[2 + pi] = b;
        }
        pa[mq][kc] = __builtin_bit_cast(bf16x8, w);
      }
    }

    bf16x8 vf[8];
#pragma unroll
    for (int i = 0; i < 8; ++i)
      vf[i] = *(const bf16x8*)(&vsm[buf][i * 1024] + lane * 16);

    __builtin_amdgcn_s_setprio(1);
#pragma unroll
    for (int kc = 0; kc < 2; ++kc)
#pragma unroll
      for (int dt = 0; dt < 4; ++dt) {
        o[0][dt] = __builtin_amdgcn_mfma_f32_16x16x32_bf16(pa[0][kc], vf[dt * 2 + kc], o[0][dt], 0, 0, 0);
        o[1][dt] = __builtin_amdgcn_mfma_f32_16x16x32_bf16(pa[1][kc], vf[dt * 2 + kc], o[1][dt], 0, 0, 0);
      }
    __builtin_amdgcn_s_setprio(0);
  };

  int buf = 0;
  stage(0, kt0);
  __syncthreads();
  for (int kt = kt0; kt < ktN; ++kt) {
    if (kt + 1 < ktN) stage(buf ^ 1, kt + 1);
    const int kv0 = kt << 6;
    if (kv0 <= q0w + 31)                       // wave-uniform causal skip
      process(buf, kv0, kv0 + 63 > q0w);
    __syncthreads();                           // drains vmcnt (next buf ready) + all reads of buf done
    buf ^= 1;
  }

  if (!multi) {
    const int b = bh >> 4, h = bh & 15;
#pragma unroll
    for (int mq = 0; mq < 2; ++mq) {
      float inv = 1.f / lr[mq];
#pragma unroll
      for (int r = 0; r < 4; ++r) {
        float ir = __shfl(inv, (g4 << 2) + r);
        int q = q0w + mq * 16 + g4 * 4 + r;
        unsigned short* rowp = attno + (size_t)(b * 2048 + q) * 1024 + h * 64;
#pragma unroll
        for (int dt = 0; dt < 4; ++dt)
          rowp[dt * 16 + r15] = f2bf(o[mq][dt][r] * ir);
      }
    }
  } else {
    const int sidx = (bh * 8 + (J - 8)) * 2 + c;
    unsigned short* po = pO + (size_t)sidx * 8192 + wave * 32 * 64;
#pragma unroll
    for (int mq = 0; mq < 2; ++mq)
#pragma unroll
      for (int r = 0; r < 4; ++r)
#pragma unroll
        for (int dt = 0; dt < 4; ++dt)
          po[(mq * 16 + g4 * 4 + r) * 64 + dt * 16 + r15] = f2bf(o[mq][dt][r]);
    if (g4 == 0) {
      float* pm = pml + sidx * 256 + wave * 32;
#pragma unroll
      for (int mq = 0; mq < 2; ++mq) {
        pm[mq * 16 + r15] = mr[mq];
        pm[128 + mq * 16 + r15] = lr[mq];
      }
    }
  }
}

// ---------- combine partials for q-blocks J>=8 (2 chunks each) ----------
__global__ __launch_bounds__(256)
void attn_combine(const unsigned short* __restrict__ pO, const float* __restrict__ pml,
                  unsigned short* __restrict__ attno) {
  const int bx = blockIdx.x;                 // 0..255 = 32 bh x 8 Jrel
  const int bh = bx >> 3, Jrel = bx & 7, J = 8 + Jrel;
  const int t = threadIdx.x;                 // 0..255
  const int row = t >> 1;                    // 0..127
  const int dh = (t & 1) << 5;               // 0 or 32
  const int s0i = (bh * 8 + Jrel) * 2;
  const float* pm0 = pml + s0i * 256;
  const float* pm1 = pm0 + 256;
  float m0 = pm0[row], l0 = pm0[128 + row];
  float m1 = pm1[row], l1 = pm1[128 + row];
  float mg = fmaxf(m0, m1);
  float s0 = exp2f(m0 - mg), s1 = exp2f(m1 - mg);
  float inv = 1.f / (l0 * s0 + l1 * s1);
  s0 *= inv; s1 *= inv;
  const unsigned short* o0 = pO + (size_t)s0i * 8192 + row * 64 + dh;
  const unsigned short* o1 = o0 + 8192;
  const int b = bh >> 4, h = bh & 15;
  const int q = J * 128 + row;
  unsigned short* dst = attno + (size_t)(b * 2048 + q) * 1024 + h * 64 + dh;
#pragma unroll
  for (int dd = 0; dd < 32; dd += 8) {
    u16x8 a = *(const u16x8*)(o0 + dd);
    u16x8 bq = *(const u16x8*)(o1 + dd);
    u16x8 ov;
#pragma unroll
    for (int e = 0; e < 8; ++e)
      ov[e] = f2bf(bf2f(a[e]) * s0 + bf2f(bq[e]) * s1);
    *(u16x8*)(dst + dd) = ov;
  }
}

// ---------- launcher ----------

extern "C" void kernel_launch(void* const* d_in, const int* in_sizes, int n_in,
                              void* d_out, int out_size, void* d_ws, size_t ws_size,
                              hipStream_t stream) {
  const float* x     = (const float*)d_in[0];
  const float* w_qkv = (const float*)d_in[1];
  const float* w_out = (const float*)d_in[2];
  float* out = (float*)d_out;

  char* ws = (char*)d_ws;
  unsigned short* xb  = (unsigned short*)(ws);                     // 8 MB  x bf16 (dead after gemm_qkv)
  unsigned short* wqT = (unsigned short*)(ws + (8u << 20));        // 6 MB  w_qkv^T (dead after gemm_qkv)
  unsigned short* woT = (unsigned short*)(ws + (14u << 20));       // 2 MB  w_out^T
  unsigned short* qb  = (unsigned short*)(ws + (16u << 20));       // 8 MB  q (roped, scaled)
  unsigned short* kb  = (unsigned short*)(ws + (24u << 20));       // 8 MB  k (roped)
  unsigned short* vt  = (unsigned short*)(ws + (32u << 20));       // 8 MB  v transposed [32][64][2048]
  unsigned short* ao  = (unsigned short*)(ws + (40u << 20));       // 8 MB  attn out [4096][1024]
  unsigned short* pO  = xb;                                        // partial O bf16 [512][128][64] (8 MB, reuse)
  float*          pml = (float*)wqT;                               // partial m/l f32 [512][256] (512 KB, reuse)

  cvt_bf16_kernel<<<2048, 256, 0, stream>>>(x, xb, 4096 * 1024);
  transpose_cvt_kernel<<<dim3(96, 32), 256, 0, stream>>>(w_qkv, wqT, 1024, 3072);
  transpose_cvt_kernel<<<dim3(32, 32), 256, 0, stream>>>(w_out, woT, 1024, 1024);
  gemm_tn<0><<<768, 256, 0, stream>>>(xb, wqT, qb, kb, vt, nullptr, 4096, 3072, 1024);
  attn_fused<<<768, 256, 0, stream>>>(qb, kb, vt, ao, pO, pml);
  attn_combine<<<256, 256, 0, stream>>>(pO, pml, ao);
  gemm_tn<1><<<256, 256, 0, stream>>>(ao, woT, nullptr, nullptr, nullptr, out, 4096, 1024, 1024);
}